// Round 2
// baseline (613.756 us; speedup 1.0000x reference)
//
#include <hip/hip_runtime.h>
#include <hip/hip_bf16.h>
#include <math.h>

// RG-LRU block: GEMM1 -> depthwise causal conv -> GEMM2 -> chunked linear scan -> GEMM3
// bf16 MFMA (16x16x32) matmuls, fp32 accumulate. bf16 intermediates in d_ws (~166 MiB).

#define HIDC 2048
#define DIMC 1024
#define BBC 4
#define TTC 2048
#define BTC (BBC*TTC)      // 8192 rows
#define NCHUNK 64
#define CLEN 32            // TTC / NCHUNK

typedef __attribute__((ext_vector_type(8))) short bfx8;
typedef __attribute__((ext_vector_type(4))) float f32x4;

__device__ __forceinline__ unsigned short f2bf(float f) {
    return __builtin_bit_cast(unsigned short, __float2bfloat16(f));
}
__device__ __forceinline__ float bf2f(unsigned short u) {
    union { unsigned int i; float f; } v; v.i = ((unsigned)u) << 16; return v.f;
}
__device__ __forceinline__ float gelu_exact(float x) {
    return 0.5f * x * (1.0f + erff(x * 0.70710678118654752f));
}

// ---------------------------------------------------------------------------
// Stage a 128x64 tile (rows x k) into LDS as bf16.
//  T=float : 16 lanes/row * float4, 8 passes, convert to bf16
//  T=ushort: 8 lanes/row * ushort8 (16B), 4 passes, raw copy
// ---------------------------------------------------------------------------
template<typename T>
__device__ __forceinline__ void stage_tile(const T* __restrict__ src, size_t ld, int k0,
                                           unsigned short* dst, int tid)
{
    if constexpr (sizeof(T) == 4) {
        const int srow = tid >> 4, scol = (tid & 15) << 2;
        #pragma unroll
        for (int p = 0; p < 8; ++p) {
            const int r = p * 16 + srow;
            const float4 v = *(const float4*)((const float*)src + (size_t)r * ld + k0 + scol);
            uint2 w;
            w.x = (unsigned)f2bf(v.x) | ((unsigned)f2bf(v.y) << 16);
            w.y = (unsigned)f2bf(v.z) | ((unsigned)f2bf(v.w) << 16);
            *(uint2*)&dst[r * 64 + scol] = w;
        }
    } else {
        const int srow = tid >> 3, scol = (tid & 7) << 3;
        #pragma unroll
        for (int p = 0; p < 4; ++p) {
            const int r = p * 32 + srow;
            const uint4 v = *(const uint4*)((const unsigned short*)src + (size_t)r * ld + k0 + scol);
            *(uint4*)&dst[r * 64 + scol] = v;
        }
    }
}

// ---------------------------------------------------------------------------
// C[M,N] = A[M,K](row-major,lda) @ B[N,K]^T(row-major,ldb) (+bias[col])
// TA/TB in {float, ushort(bf16)}; TC in {float, ushort(bf16)}.
// 128x128 tile, BK=64, 256 threads (4 waves 2x2), wave = 64x64 = 4x4 frags.
// ---------------------------------------------------------------------------
template<typename TA, typename TB, typename TC, int BIAS>
__global__ __launch_bounds__(256) void gemm_bt(
    const TA* __restrict__ A, int lda,
    const TB* __restrict__ Bm, int ldb,
    TC* __restrict__ C, int ldc,
    const float* __restrict__ bias, int K)
{
    __shared__ __align__(16) unsigned short As[128 * 64];
    __shared__ __align__(16) unsigned short Bs[128 * 64];

    const int tid  = threadIdx.x;
    const int bm   = blockIdx.y, bn = blockIdx.x;
    const int wave = tid >> 6,  lane = tid & 63;
    const int wm   = wave >> 1, wn = wave & 1;
    const int lrow = lane & 15, lq = lane >> 4;

    f32x4 acc[4][4];
    #pragma unroll
    for (int i = 0; i < 4; ++i)
        #pragma unroll
        for (int j = 0; j < 4; ++j)
            acc[i][j] = (f32x4){0.f, 0.f, 0.f, 0.f};

    const TA* Abase = A  + (size_t)(bm * 128) * lda;
    const TB* Bbase = Bm + (size_t)(bn * 128) * ldb;

    for (int k0 = 0; k0 < K; k0 += 64) {
        stage_tile<TA>(Abase, lda, k0, As, tid);
        stage_tile<TB>(Bbase, ldb, k0, Bs, tid);
        __syncthreads();
        #pragma unroll
        for (int kk = 0; kk < 2; ++kk) {
            bfx8 af[4], bfr[4];
            const int kb = kk * 32 + lq * 8;
            #pragma unroll
            for (int m = 0; m < 4; ++m)
                af[m] = *(const bfx8*)&As[(wm * 64 + m * 16 + lrow) * 64 + kb];
            #pragma unroll
            for (int n = 0; n < 4; ++n)
                bfr[n] = *(const bfx8*)&Bs[(wn * 64 + n * 16 + lrow) * 64 + kb];
            #pragma unroll
            for (int m = 0; m < 4; ++m)
                #pragma unroll
                for (int n = 0; n < 4; ++n)
                    acc[m][n] = __builtin_amdgcn_mfma_f32_16x16x32_bf16(af[m], bfr[n], acc[m][n], 0, 0, 0);
        }
        __syncthreads();
    }

    // C/D layout: col = lane&15, row = (lane>>4)*4 + reg   [m89-verified]
    #pragma unroll
    for (int m = 0; m < 4; ++m) {
        #pragma unroll
        for (int n = 0; n < 4; ++n) {
            const int row0 = bm * 128 + wm * 64 + m * 16 + lq * 4;
            const int col  = bn * 128 + wn * 64 + n * 16 + lrow;
            float bv = 0.f;
            if (BIAS) bv = bias[col];
            #pragma unroll
            for (int r = 0; r < 4; ++r) {
                const float v = acc[m][n][r] + bv;
                if constexpr (sizeof(TC) == 2)
                    C[(size_t)(row0 + r) * ldc + col] = (TC)f2bf(v);
                else
                    C[(size_t)(row0 + r) * ldc + col] = (TC)v;
            }
        }
    }
}

// ---------------------------------------------------------------------------
// causal depthwise conv, K=4: xc[bt,h] = cb[h] + sum_k w[h,k]*gi_bf[bt-3+k, 2048+h]
// one thread = 4 consecutive h
// ---------------------------------------------------------------------------
__global__ __launch_bounds__(256) void conv_k(
    const unsigned short* __restrict__ gi, const float* __restrict__ w,
    const float* __restrict__ cb, unsigned short* __restrict__ xc)
{
    const int idx = blockIdx.x * 256 + threadIdx.x;   // BTC*512
    const int h4 = idx & 511, bt = idx >> 9;
    const int h = h4 << 2;
    const int t = bt & (TTC - 1);

    float4 acc = *(const float4*)&cb[h];
    const float4 w0 = *(const float4*)&w[(h + 0) * 4];
    const float4 w1 = *(const float4*)&w[(h + 1) * 4];
    const float4 w2 = *(const float4*)&w[(h + 2) * 4];
    const float4 w3 = *(const float4*)&w[(h + 3) * 4];

    #pragma unroll
    for (int k = 0; k < 4; ++k) {
        const int tt = t - 3 + k;
        if (tt >= 0) {
            const ushort4 v = *(const ushort4*)&gi[(size_t)(bt - 3 + k) * 4096 + 2048 + h];
            const float a0 = (k == 0) ? w0.x : (k == 1) ? w0.y : (k == 2) ? w0.z : w0.w;
            const float a1 = (k == 0) ? w1.x : (k == 1) ? w1.y : (k == 2) ? w1.z : w1.w;
            const float a2 = (k == 0) ? w2.x : (k == 1) ? w2.y : (k == 2) ? w2.z : w2.w;
            const float a3 = (k == 0) ? w3.x : (k == 1) ? w3.y : (k == 2) ? w3.z : w3.w;
            acc.x += a0 * bf2f(v.x); acc.y += a1 * bf2f(v.y);
            acc.z += a2 * bf2f(v.z); acc.w += a3 * bf2f(v.w);
        }
    }
    ushort4 o;
    o.x = f2bf(acc.x); o.y = f2bf(acc.y); o.z = f2bf(acc.z); o.w = f2bf(acc.w);
    *(ushort4*)&xc[(size_t)bt * 2048 + h] = o;
}

// ---------------------------------------------------------------------------
// pass 1: per (b,chunk,h) local scan of 32 steps; emits chunk summary only
// (prefixA_end, h_local_end). No per-element state stored (recomputed in pass 3).
// ---------------------------------------------------------------------------
__global__ __launch_bounds__(256) void scan1(
    const unsigned short* __restrict__ g, const unsigned short* __restrict__ xc,
    const float* __restrict__ fb, float2* __restrict__ sums)
{
    const int idx = blockIdx.x * 256 + threadIdx.x;   // 2^19
    const int h = idx & (HIDC - 1);
    const int c = (idx >> 11) & (NCHUNK - 1);
    const int b = idx >> 17;

    const float c1 = -8.0f * log1pf(expf(fb[h]));     // ALPHA_LOG_SCALE * softplus(fb)
    float pA = 1.f, hl = 0.f;
    const int row0 = b * TTC + c * CLEN;

    for (int tl = 0; tl < CLEN; ++tl) {
        const size_t row = (size_t)(row0 + tl);
        const float f   = bf2f(g[row * 4096 + h]);
        const float gin = bf2f(g[row * 4096 + 2048 + h]);
        const float xv  = bf2f(xc[row * 2048 + h]);
        const float sf = 1.f / (1.f + expf(-f));
        const float a  = expf(c1 * sf);
        const float be = sqrtf(1.f - a * a + 1e-6f);
        const float si = 1.f / (1.f + expf(-gin));
        hl = a * hl + be * si * xv;
        pA *= a;
    }
    sums[(size_t)(c * BBC + b) * HIDC + h] = make_float2(pA, hl);
}

// ---------------------------------------------------------------------------
// pass 2: per (b,h) sequential combine of 64 chunk summaries -> carry per chunk
// ---------------------------------------------------------------------------
__global__ __launch_bounds__(256) void scan2(
    const float2* __restrict__ sums, float* __restrict__ carry)
{
    const int idx = blockIdx.x * 256 + threadIdx.x;   // BBC*HIDC = 8192
    const int h = idx & (HIDC - 1), b = idx >> 11;
    float cy = 0.f;
    for (int c = 0; c < NCHUNK; ++c) {
        carry[(size_t)(c * BBC + b) * HIDC + h] = cy;
        const float2 s = sums[(size_t)(c * BBC + b) * HIDC + h];
        cy = s.y + s.x * cy;       // h_end = hl_end + pA_end * carry_in
    }
}

// ---------------------------------------------------------------------------
// pass 3: rerun local scan seeded with carry; u = gelu(gate) * h_t, written
// in-place over gi's gate half (cols 0..2047) -> GEMM3 input with lda=4096.
// ---------------------------------------------------------------------------
__global__ __launch_bounds__(256) void scan3(
    unsigned short* __restrict__ gi, const unsigned short* __restrict__ g,
    const unsigned short* __restrict__ xc, const float* __restrict__ fb,
    const float* __restrict__ carry)
{
    const int idx = blockIdx.x * 256 + threadIdx.x;   // 2^19
    const int h = idx & (HIDC - 1);
    const int c = (idx >> 11) & (NCHUNK - 1);
    const int b = idx >> 17;

    const float c1 = -8.0f * log1pf(expf(fb[h]));
    float hh = carry[(size_t)(c * BBC + b) * HIDC + h];
    const int row0 = b * TTC + c * CLEN;

    for (int tl = 0; tl < CLEN; ++tl) {
        const size_t row = (size_t)(row0 + tl);
        const float f    = bf2f(g[row * 4096 + h]);
        const float gin  = bf2f(g[row * 4096 + 2048 + h]);
        const float xv   = bf2f(xc[row * 2048 + h]);
        const float gate = bf2f(gi[row * 4096 + h]);
        const float sf = 1.f / (1.f + expf(-f));
        const float a  = expf(c1 * sf);
        const float be = sqrtf(1.f - a * a + 1e-6f);
        const float si = 1.f / (1.f + expf(-gin));
        hh = a * hh + be * si * xv;
        gi[row * 4096 + h] = f2bf(gelu_exact(gate) * hh);
    }
}

// ---------------------------------------------------------------------------
extern "C" void kernel_launch(void* const* d_in, const int* in_sizes, int n_in,
                              void* d_out, int out_size, void* d_ws, size_t ws_size,
                              hipStream_t stream)
{
    const float* x     = (const float*)d_in[0];
    const float* W_in  = (const float*)d_in[1];
    const float* cw    = (const float*)d_in[2];
    const float* cb    = (const float*)d_in[3];
    const float* W_g   = (const float*)d_in[4];
    const float* b_g   = (const float*)d_in[5];
    const float* fb    = (const float*)d_in[6];
    const float* W_out = (const float*)d_in[7];
    float* out = (float*)d_out;

    // workspace carve-up (bf16 big buffers, fp32 small ones)
    const size_t n_gi  = (size_t)BTC * 4096;            // bf16
    const size_t n_g   = (size_t)BTC * 4096;            // bf16
    const size_t n_xc  = (size_t)BTC * 2048;            // bf16
    const size_t n_sum = (size_t)NCHUNK * BBC * HIDC;   // float2
    const size_t need = (n_gi + n_g + n_xc) * 2 + n_sum * 12;
    if (ws_size < need) return;   // graceful failure instead of OOB fault

    unsigned short* gi = (unsigned short*)d_ws;
    unsigned short* g  = gi + n_gi;
    unsigned short* xc = g + n_g;
    float2* sums  = (float2*)(xc + n_xc);
    float*  carry = (float*)(sums + n_sum);

    // GEMM1: gi = x @ W_in^T            M=8192 N=4096 K=1024
    gemm_bt<float, float, unsigned short, 0>
        <<<dim3(4096 / 128, BTC / 128), 256, 0, stream>>>(
        x, DIMC, W_in, DIMC, gi, 4096, nullptr, DIMC);

    // depthwise causal conv on gi[:, 2048:] -> xc
    conv_k<<<(BTC * 512) / 256, 256, 0, stream>>>(gi, cw, cb, xc);

    // GEMM2: g = xc @ W_g^T + b_g       M=8192 N=4096 K=2048
    gemm_bt<unsigned short, float, unsigned short, 1>
        <<<dim3(4096 / 128, BTC / 128), 256, 0, stream>>>(
        xc, HIDC, W_g, HIDC, g, 4096, b_g, HIDC);

    // chunked linear recurrence (summaries -> carries -> recompute+fuse gelu)
    scan1<<<(BBC * NCHUNK * HIDC) / 256, 256, 0, stream>>>(g, xc, fb, sums);
    scan2<<<(BBC * HIDC) / 256, 256, 0, stream>>>(sums, carry);
    scan3<<<(BBC * NCHUNK * HIDC) / 256, 256, 0, stream>>>(gi, g, xc, fb, carry);

    // GEMM3: out = u @ W_out^T          M=8192 N=1024 K=2048 (u in gi cols 0..2047)
    gemm_bt<unsigned short, float, float, 0>
        <<<dim3(DIMC / 128, BTC / 128), 256, 0, stream>>>(
        gi, 4096, W_out, HIDC, out, DIMC, nullptr, HIDC);
}

// Round 3
// 531.246 us; speedup vs baseline: 1.1553x; 1.1553x over previous
//
#include <hip/hip_runtime.h>
#include <hip/hip_bf16.h>
#include <math.h>

// RG-LRU block: GEMM1 -> depthwise causal conv -> GEMM2 -> chunked linear scan -> GEMM3
// bf16 MFMA (16x16x32), fp32 accumulate. Weights pre-converted to bf16 so GEMM
// staging uses global_load_lds (16B direct-to-LDS DMA, m97 structure).

#define HIDC 2048
#define DIMC 1024
#define BBC 4
#define TTC 2048
#define BTC (BBC*TTC)      // 8192 rows
#define NCHUNK 64
#define CLEN 32            // TTC / NCHUNK

typedef __attribute__((ext_vector_type(8))) short bfx8;
typedef __attribute__((ext_vector_type(4))) float f32x4;

__device__ __forceinline__ unsigned short f2bf(float f) {
    return __builtin_bit_cast(unsigned short, __float2bfloat16(f));
}
__device__ __forceinline__ float bf2f(unsigned short u) {
    union { unsigned int i; float f; } v; v.i = ((unsigned)u) << 16; return v.f;
}
__device__ __forceinline__ float gelu_exact(float x) {
    return 0.5f * x * (1.0f + erff(x * 0.70710678118654752f));
}

typedef const unsigned int __attribute__((address_space(1)))* gas_ptr;
typedef unsigned int __attribute__((address_space(3)))* las_ptr;
__device__ __forceinline__ void gload_lds16(const void* g, void* l) {
    // 16B/lane direct global->LDS; LDS dest = wave-uniform base + lane*16
    __builtin_amdgcn_global_load_lds((gas_ptr)g, (las_ptr)l, 16, 0, 0);
}

// ---------------------------------------------------------------------------
// Stage a 128x64 bf16 tile into linear LDS.
//  T=ushort (bf16 source): 4x global_load_lds 16B per wave (m97 path)
//  T=float  (fp32 source): reg-stage + convert + ds_write
// ---------------------------------------------------------------------------
template<typename T>
__device__ __forceinline__ void stage_op(const T* __restrict__ base, int ld, int k0,
                                         unsigned short* lds, int tid)
{
    if constexpr (sizeof(T) == 2) {
        const int wave = tid >> 6, lane = tid & 63;
        const int grow = lane >> 3;          // row within 8-row group
        const int gcol = (lane & 7) << 3;    // bf16 col (16B granules)
        #pragma unroll
        for (int j = 0; j < 4; ++j) {
            const int r0 = wave * 32 + j * 8;
            gload_lds16((const unsigned short*)base + (size_t)(r0 + grow) * ld + k0 + gcol,
                        &lds[r0 * 64]);
        }
    } else {
        const int srow = tid >> 4, scol = (tid & 15) << 2;
        #pragma unroll
        for (int p = 0; p < 8; ++p) {
            const int r = p * 16 + srow;
            const float4 v = *(const float4*)((const float*)base + (size_t)r * ld + k0 + scol);
            uint2 w;
            w.x = (unsigned)f2bf(v.x) | ((unsigned)f2bf(v.y) << 16);
            w.y = (unsigned)f2bf(v.z) | ((unsigned)f2bf(v.w) << 16);
            *(uint2*)&lds[r * 64 + scol] = w;
        }
    }
}

// ---------------------------------------------------------------------------
// C[M,N] = A[M,K](row-major,lda) @ B[N,K]^T(row-major,ldb) (+bias[col])
// 128x128 tile, BK=64, 256 threads (4 waves 2x2), wave = 64x64 = 4x4 frags.
// ---------------------------------------------------------------------------
template<typename TA, typename TB, typename TC, int BIAS>
__global__ __launch_bounds__(256) void gemm_bt(
    const TA* __restrict__ A, int lda,
    const TB* __restrict__ Bm, int ldb,
    TC* __restrict__ C, int ldc,
    const float* __restrict__ bias, int K)
{
    __shared__ __align__(16) unsigned short As[128 * 64];
    __shared__ __align__(16) unsigned short Bs[128 * 64];

    const int tid  = threadIdx.x;
    const int bm   = blockIdx.y, bn = blockIdx.x;
    const int wave = tid >> 6,  lane = tid & 63;
    const int wm   = wave >> 1, wn = wave & 1;
    const int lrow = lane & 15, lq = lane >> 4;

    f32x4 acc[4][4];
    #pragma unroll
    for (int i = 0; i < 4; ++i)
        #pragma unroll
        for (int j = 0; j < 4; ++j)
            acc[i][j] = (f32x4){0.f, 0.f, 0.f, 0.f};

    const TA* Abase = A  + (size_t)(bm * 128) * lda;
    const TB* Bbase = Bm + (size_t)(bn * 128) * ldb;

    for (int k0 = 0; k0 < K; k0 += 64) {
        stage_op<TA>(Abase, lda, k0, As, tid);
        stage_op<TB>(Bbase, ldb, k0, Bs, tid);
        __syncthreads();
        #pragma unroll
        for (int kk = 0; kk < 2; ++kk) {
            bfx8 af[4], bfr[4];
            const int kb = kk * 32 + lq * 8;
            #pragma unroll
            for (int m = 0; m < 4; ++m)
                af[m] = *(const bfx8*)&As[(wm * 64 + m * 16 + lrow) * 64 + kb];
            #pragma unroll
            for (int n = 0; n < 4; ++n)
                bfr[n] = *(const bfx8*)&Bs[(wn * 64 + n * 16 + lrow) * 64 + kb];
            #pragma unroll
            for (int m = 0; m < 4; ++m)
                #pragma unroll
                for (int n = 0; n < 4; ++n)
                    acc[m][n] = __builtin_amdgcn_mfma_f32_16x16x32_bf16(af[m], bfr[n], acc[m][n], 0, 0, 0);
        }
        __syncthreads();
    }

    // C/D layout: col = lane&15, row = (lane>>4)*4 + reg   [m89-verified]
    #pragma unroll
    for (int m = 0; m < 4; ++m) {
        #pragma unroll
        for (int n = 0; n < 4; ++n) {
            const int row0 = bm * 128 + wm * 64 + m * 16 + lq * 4;
            const int col  = bn * 128 + wn * 64 + n * 16 + lrow;
            float bv = 0.f;
            if (BIAS) bv = bias[col];
            #pragma unroll
            for (int r = 0; r < 4; ++r) {
                const float v = acc[m][n][r] + bv;
                if constexpr (sizeof(TC) == 2)
                    C[(size_t)(row0 + r) * ldc + col] = (TC)f2bf(v);
                else
                    C[(size_t)(row0 + r) * ldc + col] = (TC)v;
            }
        }
    }
}

// ---------------------------------------------------------------------------
// fp32 -> bf16 elementwise convert, 8 elems/thread
// ---------------------------------------------------------------------------
__global__ __launch_bounds__(256) void cvt_bf16(
    const float* __restrict__ in, unsigned short* __restrict__ out, int n8)
{
    const int i = blockIdx.x * 256 + threadIdx.x;
    if (i >= n8) return;
    const float4 a = ((const float4*)in)[i * 2];
    const float4 b = ((const float4*)in)[i * 2 + 1];
    uint4 w;
    w.x = (unsigned)f2bf(a.x) | ((unsigned)f2bf(a.y) << 16);
    w.y = (unsigned)f2bf(a.z) | ((unsigned)f2bf(a.w) << 16);
    w.z = (unsigned)f2bf(b.x) | ((unsigned)f2bf(b.y) << 16);
    w.w = (unsigned)f2bf(b.z) | ((unsigned)f2bf(b.w) << 16);
    ((uint4*)out)[i] = w;
}

// ---------------------------------------------------------------------------
// causal depthwise conv, K=4: xc[bt,h] = cb[h] + sum_k w[h,k]*gi_bf[bt-3+k, 2048+h]
// ---------------------------------------------------------------------------
__global__ __launch_bounds__(256) void conv_k(
    const unsigned short* __restrict__ gi, const float* __restrict__ w,
    const float* __restrict__ cb, unsigned short* __restrict__ xc)
{
    const int idx = blockIdx.x * 256 + threadIdx.x;   // BTC*512
    const int h4 = idx & 511, bt = idx >> 9;
    const int h = h4 << 2;
    const int t = bt & (TTC - 1);

    float4 acc = *(const float4*)&cb[h];
    const float4 w0 = *(const float4*)&w[(h + 0) * 4];
    const float4 w1 = *(const float4*)&w[(h + 1) * 4];
    const float4 w2 = *(const float4*)&w[(h + 2) * 4];
    const float4 w3 = *(const float4*)&w[(h + 3) * 4];

    #pragma unroll
    for (int k = 0; k < 4; ++k) {
        const int tt = t - 3 + k;
        if (tt >= 0) {
            const ushort4 v = *(const ushort4*)&gi[(size_t)(bt - 3 + k) * 4096 + 2048 + h];
            const float a0 = (k == 0) ? w0.x : (k == 1) ? w0.y : (k == 2) ? w0.z : w0.w;
            const float a1 = (k == 0) ? w1.x : (k == 1) ? w1.y : (k == 2) ? w1.z : w1.w;
            const float a2 = (k == 0) ? w2.x : (k == 1) ? w2.y : (k == 2) ? w2.z : w2.w;
            const float a3 = (k == 0) ? w3.x : (k == 1) ? w3.y : (k == 2) ? w3.z : w3.w;
            acc.x += a0 * bf2f(v.x); acc.y += a1 * bf2f(v.y);
            acc.z += a2 * bf2f(v.z); acc.w += a3 * bf2f(v.w);
        }
    }
    ushort4 o;
    o.x = f2bf(acc.x); o.y = f2bf(acc.y); o.z = f2bf(acc.z); o.w = f2bf(acc.w);
    *(ushort4*)&xc[(size_t)bt * 2048 + h] = o;
}

// ---------------------------------------------------------------------------
// pass 1: per (b,chunk,h) local scan of 32 steps; emits chunk summary only
// ---------------------------------------------------------------------------
__global__ __launch_bounds__(256) void scan1(
    const unsigned short* __restrict__ g, const unsigned short* __restrict__ xc,
    const float* __restrict__ fb, float2* __restrict__ sums)
{
    const int idx = blockIdx.x * 256 + threadIdx.x;   // 2^19
    const int h = idx & (HIDC - 1);
    const int c = (idx >> 11) & (NCHUNK - 1);
    const int b = idx >> 17;

    const float c1 = -8.0f * log1pf(expf(fb[h]));     // ALPHA_LOG_SCALE * softplus(fb)
    float pA = 1.f, hl = 0.f;
    const int row0 = b * TTC + c * CLEN;

    for (int tl = 0; tl < CLEN; ++tl) {
        const size_t row = (size_t)(row0 + tl);
        const float f   = bf2f(g[row * 4096 + h]);
        const float gin = bf2f(g[row * 4096 + 2048 + h]);
        const float xv  = bf2f(xc[row * 2048 + h]);
        const float sf = 1.f / (1.f + expf(-f));
        const float a  = expf(c1 * sf);
        const float be = sqrtf(1.f - a * a + 1e-6f);
        const float si = 1.f / (1.f + expf(-gin));
        hl = a * hl + be * si * xv;
        pA *= a;
    }
    sums[(size_t)(c * BBC + b) * HIDC + h] = make_float2(pA, hl);
}

// ---------------------------------------------------------------------------
// pass 2: per (b,h) sequential combine of 64 chunk summaries -> carry per chunk
// ---------------------------------------------------------------------------
__global__ __launch_bounds__(256) void scan2(
    const float2* __restrict__ sums, float* __restrict__ carry)
{
    const int idx = blockIdx.x * 256 + threadIdx.x;   // BBC*HIDC = 8192
    const int h = idx & (HIDC - 1), b = idx >> 11;
    float cy = 0.f;
    for (int c = 0; c < NCHUNK; ++c) {
        carry[(size_t)(c * BBC + b) * HIDC + h] = cy;
        const float2 s = sums[(size_t)(c * BBC + b) * HIDC + h];
        cy = s.y + s.x * cy;       // h_end = hl_end + pA_end * carry_in
    }
}

// ---------------------------------------------------------------------------
// pass 3: rerun local scan seeded with carry; u = gelu(gate)*h_t written
// in-place over gi's gate half (cols 0..2047) -> GEMM3 input with lda=4096.
// ---------------------------------------------------------------------------
__global__ __launch_bounds__(256) void scan3(
    unsigned short* __restrict__ gi, const unsigned short* __restrict__ g,
    const unsigned short* __restrict__ xc, const float* __restrict__ fb,
    const float* __restrict__ carry)
{
    const int idx = blockIdx.x * 256 + threadIdx.x;   // 2^19
    const int h = idx & (HIDC - 1);
    const int c = (idx >> 11) & (NCHUNK - 1);
    const int b = idx >> 17;

    const float c1 = -8.0f * log1pf(expf(fb[h]));
    float hh = carry[(size_t)(c * BBC + b) * HIDC + h];
    const int row0 = b * TTC + c * CLEN;

    for (int tl = 0; tl < CLEN; ++tl) {
        const size_t row = (size_t)(row0 + tl);
        const float f    = bf2f(g[row * 4096 + h]);
        const float gin  = bf2f(g[row * 4096 + 2048 + h]);
        const float xv   = bf2f(xc[row * 2048 + h]);
        const float gate = bf2f(gi[row * 4096 + h]);
        const float sf = 1.f / (1.f + expf(-f));
        const float a  = expf(c1 * sf);
        const float be = sqrtf(1.f - a * a + 1e-6f);
        const float si = 1.f / (1.f + expf(-gin));
        hh = a * hh + be * si * xv;
        gi[row * 4096 + h] = f2bf(gelu_exact(gate) * hh);
    }
}

// ---------------------------------------------------------------------------
extern "C" void kernel_launch(void* const* d_in, const int* in_sizes, int n_in,
                              void* d_out, int out_size, void* d_ws, size_t ws_size,
                              hipStream_t stream)
{
    const float* x     = (const float*)d_in[0];
    const float* W_in  = (const float*)d_in[1];
    const float* cw    = (const float*)d_in[2];
    const float* cb    = (const float*)d_in[3];
    const float* W_g   = (const float*)d_in[4];
    const float* b_g   = (const float*)d_in[5];
    const float* fb    = (const float*)d_in[6];
    const float* W_out = (const float*)d_in[7];
    float* out = (float*)d_out;

    const size_t n_gi  = (size_t)BTC * 4096;            // bf16
    const size_t n_g   = (size_t)BTC * 4096;            // bf16
    const size_t n_xc  = (size_t)BTC * 2048;            // bf16
    const size_t n_sum = (size_t)NCHUNK * BBC * HIDC;   // float2
    const size_t nWin  = (size_t)4096 * 1024;
    const size_t nWg   = (size_t)4096 * 2048;
    const size_t nWout = (size_t)1024 * 2048;
    const size_t need_base = (n_gi + n_g + n_xc) * 2 + n_sum * 12;           // 166 MiB
    const size_t need_full = need_base + (nWin + nWg + nWout) * 2;           // 194 MiB
    if (ws_size < need_base) return;
    const bool bfw = (ws_size >= need_full);

    unsigned short* gi = (unsigned short*)d_ws;
    unsigned short* g  = gi + n_gi;
    unsigned short* xc = g + n_g;
    float2* sums  = (float2*)(xc + n_xc);
    float*  carry = (float*)(sums + n_sum);
    unsigned short* win_bf  = (unsigned short*)(carry + n_sum);
    unsigned short* wg_bf   = win_bf + nWin;
    unsigned short* wout_bf = wg_bf + nWg;

    if (bfw) {
        cvt_bf16<<<(int)(nWin  / 8 / 256), 256, 0, stream>>>(W_in,  win_bf,  (int)(nWin  / 8));
        cvt_bf16<<<(int)(nWg   / 8 / 256), 256, 0, stream>>>(W_g,   wg_bf,   (int)(nWg   / 8));
        cvt_bf16<<<(int)(nWout / 8 / 256), 256, 0, stream>>>(W_out, wout_bf, (int)(nWout / 8));
    }

    // GEMM1: gi = x @ W_in^T            M=8192 N=4096 K=1024
    if (bfw)
        gemm_bt<float, unsigned short, unsigned short, 0>
            <<<dim3(4096 / 128, BTC / 128), 256, 0, stream>>>(
            x, DIMC, win_bf, DIMC, gi, 4096, nullptr, DIMC);
    else
        gemm_bt<float, float, unsigned short, 0>
            <<<dim3(4096 / 128, BTC / 128), 256, 0, stream>>>(
            x, DIMC, W_in, DIMC, gi, 4096, nullptr, DIMC);

    // depthwise causal conv on gi[:, 2048:] -> xc
    conv_k<<<(BTC * 512) / 256, 256, 0, stream>>>(gi, cw, cb, xc);

    // GEMM2: g = xc @ W_g^T + b_g       M=8192 N=4096 K=2048
    if (bfw)
        gemm_bt<unsigned short, unsigned short, unsigned short, 1>
            <<<dim3(4096 / 128, BTC / 128), 256, 0, stream>>>(
            xc, HIDC, wg_bf, HIDC, g, 4096, b_g, HIDC);
    else
        gemm_bt<unsigned short, float, unsigned short, 1>
            <<<dim3(4096 / 128, BTC / 128), 256, 0, stream>>>(
            xc, HIDC, W_g, HIDC, g, 4096, b_g, HIDC);

    // chunked linear recurrence (summaries -> carries -> recompute+fuse gelu)
    scan1<<<(BBC * NCHUNK * HIDC) / 256, 256, 0, stream>>>(g, xc, fb, sums);
    scan2<<<(BBC * HIDC) / 256, 256, 0, stream>>>(sums, carry);
    scan3<<<(BBC * NCHUNK * HIDC) / 256, 256, 0, stream>>>(gi, g, xc, fb, carry);

    // GEMM3: out = u @ W_out^T          M=8192 N=1024 K=2048 (u in gi cols 0..2047)
    if (bfw)
        gemm_bt<unsigned short, unsigned short, float, 0>
            <<<dim3(DIMC / 128, BTC / 128), 256, 0, stream>>>(
            gi, 4096, wout_bf, HIDC, out, DIMC, nullptr, HIDC);
    else
        gemm_bt<unsigned short, float, float, 0>
            <<<dim3(DIMC / 128, BTC / 128), 256, 0, stream>>>(
            gi, 4096, W_out, HIDC, out, DIMC, nullptr, HIDC);
}

// Round 4
// 435.430 us; speedup vs baseline: 1.4095x; 1.2200x over previous
//
#include <hip/hip_runtime.h>
#include <hip/hip_bf16.h>
#include <math.h>

// RG-LRU block: GEMM1 -> depthwise causal conv -> GEMM2 -> chunked linear scan -> GEMM3
// GEMMs: 256x256-tile 8-phase bf16 MFMA kernel (T2 swizzle + T3/T4 counted-vmcnt + T5 setprio).
// Workspace 186 MiB; falls back to the round-3 128x128 kernel if ws is smaller.

#define HIDC 2048
#define DIMC 1024
#define BBC 4
#define TTC 2048
#define BTC (BBC*TTC)      // 8192 rows
#define NCHUNK 64
#define CLEN 32            // TTC / NCHUNK

typedef __attribute__((ext_vector_type(8))) short bfx8;
typedef __attribute__((ext_vector_type(4))) float f32x4;

__device__ __forceinline__ unsigned short f2bf(float f) {
    return __builtin_bit_cast(unsigned short, __float2bfloat16(f));
}
__device__ __forceinline__ float bf2f(unsigned short u) {
    union { unsigned int i; float f; } v; v.i = ((unsigned)u) << 16; return v.f;
}
__device__ __forceinline__ float gelu_exact(float x) {
    return 0.5f * x * (1.0f + erff(x * 0.70710678118654752f));
}

typedef const unsigned int __attribute__((address_space(1)))* gas_ptr;
typedef unsigned int __attribute__((address_space(3)))* las_ptr;
__device__ __forceinline__ void gload_lds16(const void* g, void* l) {
    // 16B/lane direct global->LDS; LDS dest = wave-uniform base + lane*16
    __builtin_amdgcn_global_load_lds((gas_ptr)g, (las_ptr)l, 16, 0, 0);
}

// ===========================================================================
// 256x256-tile, BK=64, 8-wave (2Mx4N), 8-phase K-loop GEMM.
// C[M,N] = A[M,K] @ B[N,K]^T (+bias). A,B bf16 row-major; C bf16 or f32.
// LDS: 2 dbuf x (A 256x64 + B 256x64) bf16 = 128 KiB.
// Swizzle: LDS element (r, c) holds global (r, c ^ ((r&7)<<3)); gload_lds
// keeps LDS linear, the global SOURCE col is pre-swizzled per-lane (m173),
// ds_read applies the same XOR -> exactly 8 lanes/16B-granule (conflict-free).
// ===========================================================================
__device__ __forceinline__ void stage_half_sw(
    const unsigned short* __restrict__ gsrc,  // per-lane: row (half_row0+grow), swizzled col, k1 added
    int ld, unsigned short* ldsdst, int wave)
{
    #pragma unroll
    for (int j = 0; j < 2; ++j) {
        const int r0 = (wave * 2 + j) * 8;     // 8 rows per gload, 2 gloads/wave, 8 waves = 128 rows
        gload_lds16(gsrc + (size_t)r0 * ld, ldsdst + r0 * 64);
    }
}

template<typename TC, int BIAS>
__global__ __launch_bounds__(512, 2) void gemm8p(
    const unsigned short* __restrict__ A, int lda,
    const unsigned short* __restrict__ Bm, int ldb,
    TC* __restrict__ C, int ldc,
    const float* __restrict__ bias, int K)
{
    __shared__ __align__(16) unsigned short lds[2][2][256 * 64]; // [buf][A/B]

    const int tid  = threadIdx.x;
    const int bm   = blockIdx.y, bn = blockIdx.x;
    const int wave = tid >> 6,  lane = tid & 63;
    const int wm   = wave >> 2, wn = wave & 3;       // 2 x 4 waves, each 128x64 of C
    const int lrow = lane & 15, lq = lane >> 4;

    // ds_read swizzled column offsets (elements)
    const int key = (lrow & 7) << 3;
    const int e0  = (lq << 3) ^ key;
    const int e1  = e0 ^ 32;
    const int aRd = (wm * 128 + lrow) * 64;
    const int bRd = (wn * 64 + lrow) * 64;

    // stage addressing: lane covers row grow of each 8-row group, swizzled col
    const int grow = lane >> 3;
    const int gswz = ((lane & 7) ^ (grow & 7)) << 3;
    const unsigned short* aSrc = A  + (size_t)(bm * 256 + grow) * lda + gswz;
    const unsigned short* bSrc = Bm + (size_t)(bn * 256 + grow) * ldb + gswz;

    f32x4 acc[8][4];
    #pragma unroll
    for (int i = 0; i < 8; ++i)
        #pragma unroll
        for (int n = 0; n < 4; ++n)
            acc[i][n] = (f32x4){0.f, 0.f, 0.f, 0.f};

    bfx8 areg[4][2], b0r[2][2], b1r[2][2];

    const int NT = K >> 6;

    // prologue: stage K-tile 0 into buf 0 (4 half-tiles, 8 loads/wave)
    stage_half_sw(aSrc,                        lda, &lds[0][0][0],        wave);
    stage_half_sw(aSrc + (size_t)128 * lda,    lda, &lds[0][0][128 * 64], wave);
    stage_half_sw(bSrc,                        ldb, &lds[0][1][0],        wave);
    stage_half_sw(bSrc + (size_t)128 * ldb,    ldb, &lds[0][1][128 * 64], wave);

    for (int t = 0; t < NT; ++t) {
        const int cur = t & 1, nxt = cur ^ 1;
        const unsigned short* Ac = lds[cur][0];
        const unsigned short* Bc = lds[cur][1];
        const bool hn = (t + 1 < NT);
        const int k1 = (t + 1) << 6;

        // ---- phase 0: stage A-half0(t+1); wait cur's 8 loads; MFMA A[0..3] x B[0..1]
        if (hn) stage_half_sw(aSrc + k1, lda, &lds[nxt][0][0], wave);
        if (hn) { asm volatile("s_waitcnt vmcnt(2)" ::: "memory"); }
        else    { asm volatile("s_waitcnt vmcnt(0)" ::: "memory"); }
        __builtin_amdgcn_sched_barrier(0);
        __builtin_amdgcn_s_barrier();
        __builtin_amdgcn_sched_barrier(0);
        #pragma unroll
        for (int i = 0; i < 4; ++i) {
            areg[i][0] = *(const bfx8*)(Ac + aRd + i * 1024 + e0);
            areg[i][1] = *(const bfx8*)(Ac + aRd + i * 1024 + e1);
        }
        #pragma unroll
        for (int n = 0; n < 2; ++n) {
            b0r[n][0] = *(const bfx8*)(Bc + bRd + n * 1024 + e0);
            b0r[n][1] = *(const bfx8*)(Bc + bRd + n * 1024 + e1);
        }
        __builtin_amdgcn_s_setprio(1);
        #pragma unroll
        for (int i = 0; i < 4; ++i)
            #pragma unroll
            for (int n = 0; n < 2; ++n)
                #pragma unroll
                for (int kk = 0; kk < 2; ++kk)
                    acc[i][n] = __builtin_amdgcn_mfma_f32_16x16x32_bf16(areg[i][kk], b0r[n][kk], acc[i][n], 0, 0, 0);
        __builtin_amdgcn_s_setprio(0);
        __builtin_amdgcn_sched_barrier(0);
        __builtin_amdgcn_s_barrier();
        __builtin_amdgcn_sched_barrier(0);

        // ---- phase 1: stage A-half1(t+1); MFMA A[0..3] x B[2..3]
        if (hn) stage_half_sw(aSrc + (size_t)128 * lda + k1, lda, &lds[nxt][0][128 * 64], wave);
        #pragma unroll
        for (int n = 0; n < 2; ++n) {
            b1r[n][0] = *(const bfx8*)(Bc + bRd + (2 + n) * 1024 + e0);
            b1r[n][1] = *(const bfx8*)(Bc + bRd + (2 + n) * 1024 + e1);
        }
        __builtin_amdgcn_s_setprio(1);
        #pragma unroll
        for (int i = 0; i < 4; ++i)
            #pragma unroll
            for (int n = 0; n < 2; ++n)
                #pragma unroll
                for (int kk = 0; kk < 2; ++kk)
                    acc[i][2 + n] = __builtin_amdgcn_mfma_f32_16x16x32_bf16(areg[i][kk], b1r[n][kk], acc[i][2 + n], 0, 0, 0);
        __builtin_amdgcn_s_setprio(0);
        __builtin_amdgcn_sched_barrier(0);
        __builtin_amdgcn_s_barrier();
        __builtin_amdgcn_sched_barrier(0);

        // ---- phase 2: stage B-half0(t+1); MFMA A[4..7] x B[2..3]
        if (hn) stage_half_sw(bSrc + k1, ldb, &lds[nxt][1][0], wave);
        #pragma unroll
        for (int i = 0; i < 4; ++i) {
            areg[i][0] = *(const bfx8*)(Ac + aRd + (4 + i) * 1024 + e0);
            areg[i][1] = *(const bfx8*)(Ac + aRd + (4 + i) * 1024 + e1);
        }
        __builtin_amdgcn_s_setprio(1);
        #pragma unroll
        for (int i = 0; i < 4; ++i)
            #pragma unroll
            for (int n = 0; n < 2; ++n)
                #pragma unroll
                for (int kk = 0; kk < 2; ++kk)
                    acc[4 + i][2 + n] = __builtin_amdgcn_mfma_f32_16x16x32_bf16(areg[i][kk], b1r[n][kk], acc[4 + i][2 + n], 0, 0, 0);
        __builtin_amdgcn_s_setprio(0);
        __builtin_amdgcn_sched_barrier(0);
        __builtin_amdgcn_s_barrier();
        __builtin_amdgcn_sched_barrier(0);

        // ---- phase 3: stage B-half1(t+1); MFMA A[4..7] x B[0..1]
        if (hn) stage_half_sw(bSrc + (size_t)128 * ldb + k1, ldb, &lds[nxt][1][128 * 64], wave);
        __builtin_amdgcn_s_setprio(1);
        #pragma unroll
        for (int i = 0; i < 4; ++i)
            #pragma unroll
            for (int n = 0; n < 2; ++n)
                #pragma unroll
                for (int kk = 0; kk < 2; ++kk)
                    acc[4 + i][n] = __builtin_amdgcn_mfma_f32_16x16x32_bf16(areg[i][kk], b0r[n][kk], acc[4 + i][n], 0, 0, 0);
        __builtin_amdgcn_s_setprio(0);
        __builtin_amdgcn_sched_barrier(0);
        __builtin_amdgcn_s_barrier();
        __builtin_amdgcn_sched_barrier(0);
    }

    // epilogue: C/D layout col=lane&15, row=(lane>>4)*4+reg
    #pragma unroll
    for (int i = 0; i < 8; ++i) {
        const int row0 = bm * 256 + wm * 128 + i * 16 + lq * 4;
        #pragma unroll
        for (int n = 0; n < 4; ++n) {
            const int col = bn * 256 + wn * 64 + n * 16 + lrow;
            float bv = 0.f;
            if (BIAS) bv = bias[col];
            #pragma unroll
            for (int r = 0; r < 4; ++r) {
                const float v = acc[i][n][r] + bv;
                if constexpr (sizeof(TC) == 2)
                    C[(size_t)(row0 + r) * ldc + col] = (TC)f2bf(v);
                else
                    C[(size_t)(row0 + r) * ldc + col] = (TC)v;
            }
        }
    }
}

// ===========================================================================
// Fallback 128x128 GEMM (round-3 proven) for small workspace
// ===========================================================================
template<typename T>
__device__ __forceinline__ void stage_op(const T* __restrict__ base, int ld, int k0,
                                         unsigned short* lds_, int tid)
{
    if constexpr (sizeof(T) == 2) {
        const int wave = tid >> 6, lane = tid & 63;
        const int grow = lane >> 3;
        const int gcol = (lane & 7) << 3;
        #pragma unroll
        for (int j = 0; j < 4; ++j) {
            const int r0 = wave * 32 + j * 8;
            gload_lds16((const unsigned short*)base + (size_t)(r0 + grow) * ld + k0 + gcol,
                        &lds_[r0 * 64]);
        }
    } else {
        const int srow = tid >> 4, scol = (tid & 15) << 2;
        #pragma unroll
        for (int p = 0; p < 8; ++p) {
            const int r = p * 16 + srow;
            const float4 v = *(const float4*)((const float*)base + (size_t)r * ld + k0 + scol);
            uint2 w;
            w.x = (unsigned)f2bf(v.x) | ((unsigned)f2bf(v.y) << 16);
            w.y = (unsigned)f2bf(v.z) | ((unsigned)f2bf(v.w) << 16);
            *(uint2*)&lds_[r * 64 + scol] = w;
        }
    }
}

template<typename TA, typename TB, typename TC, int BIAS>
__global__ __launch_bounds__(256) void gemm_bt(
    const TA* __restrict__ A, int lda,
    const TB* __restrict__ Bm, int ldb,
    TC* __restrict__ C, int ldc,
    const float* __restrict__ bias, int K)
{
    __shared__ __align__(16) unsigned short As[128 * 64];
    __shared__ __align__(16) unsigned short Bs[128 * 64];

    const int tid  = threadIdx.x;
    const int bm   = blockIdx.y, bn = blockIdx.x;
    const int wave = tid >> 6,  lane = tid & 63;
    const int wm   = wave >> 1, wn = wave & 1;
    const int lrow = lane & 15, lq = lane >> 4;

    f32x4 acc[4][4];
    #pragma unroll
    for (int i = 0; i < 4; ++i)
        #pragma unroll
        for (int j = 0; j < 4; ++j)
            acc[i][j] = (f32x4){0.f, 0.f, 0.f, 0.f};

    const TA* Abase = A  + (size_t)(bm * 128) * lda;
    const TB* Bbase = Bm + (size_t)(bn * 128) * ldb;

    for (int k0 = 0; k0 < K; k0 += 64) {
        stage_op<TA>(Abase, lda, k0, As, tid);
        stage_op<TB>(Bbase, ldb, k0, Bs, tid);
        __syncthreads();
        #pragma unroll
        for (int kk = 0; kk < 2; ++kk) {
            bfx8 af[4], bfr[4];
            const int kb = kk * 32 + lq * 8;
            #pragma unroll
            for (int m = 0; m < 4; ++m)
                af[m] = *(const bfx8*)&As[(wm * 64 + m * 16 + lrow) * 64 + kb];
            #pragma unroll
            for (int n = 0; n < 4; ++n)
                bfr[n] = *(const bfx8*)&Bs[(wn * 64 + n * 16 + lrow) * 64 + kb];
            #pragma unroll
            for (int m = 0; m < 4; ++m)
                #pragma unroll
                for (int n = 0; n < 4; ++n)
                    acc[m][n] = __builtin_amdgcn_mfma_f32_16x16x32_bf16(af[m], bfr[n], acc[m][n], 0, 0, 0);
        }
        __syncthreads();
    }

    #pragma unroll
    for (int m = 0; m < 4; ++m) {
        #pragma unroll
        for (int n = 0; n < 4; ++n) {
            const int row0 = bm * 128 + wm * 64 + m * 16 + lq * 4;
            const int col  = bn * 128 + wn * 64 + n * 16 + lrow;
            float bv = 0.f;
            if (BIAS) bv = bias[col];
            #pragma unroll
            for (int r = 0; r < 4; ++r) {
                const float v = acc[m][n][r] + bv;
                if constexpr (sizeof(TC) == 2)
                    C[(size_t)(row0 + r) * ldc + col] = (TC)f2bf(v);
                else
                    C[(size_t)(row0 + r) * ldc + col] = (TC)v;
            }
        }
    }
}

// ---------------------------------------------------------------------------
// fp32 -> bf16 elementwise convert, 8 elems/thread
// ---------------------------------------------------------------------------
__global__ __launch_bounds__(256) void cvt_bf16(
    const float* __restrict__ in, unsigned short* __restrict__ out, int n8)
{
    const int i = blockIdx.x * 256 + threadIdx.x;
    if (i >= n8) return;
    const float4 a = ((const float4*)in)[i * 2];
    const float4 b = ((const float4*)in)[i * 2 + 1];
    uint4 w;
    w.x = (unsigned)f2bf(a.x) | ((unsigned)f2bf(a.y) << 16);
    w.y = (unsigned)f2bf(a.z) | ((unsigned)f2bf(a.w) << 16);
    w.z = (unsigned)f2bf(b.x) | ((unsigned)f2bf(b.y) << 16);
    w.w = (unsigned)f2bf(b.z) | ((unsigned)f2bf(b.w) << 16);
    ((uint4*)out)[i] = w;
}

// ---------------------------------------------------------------------------
// causal depthwise conv, K=4
// ---------------------------------------------------------------------------
__global__ __launch_bounds__(256) void conv_k(
    const unsigned short* __restrict__ gi, const float* __restrict__ w,
    const float* __restrict__ cb, unsigned short* __restrict__ xc)
{
    const int idx = blockIdx.x * 256 + threadIdx.x;   // BTC*512
    const int h4 = idx & 511, bt = idx >> 9;
    const int h = h4 << 2;
    const int t = bt & (TTC - 1);

    float4 acc = *(const float4*)&cb[h];
    const float4 w0 = *(const float4*)&w[(h + 0) * 4];
    const float4 w1 = *(const float4*)&w[(h + 1) * 4];
    const float4 w2 = *(const float4*)&w[(h + 2) * 4];
    const float4 w3 = *(const float4*)&w[(h + 3) * 4];

    #pragma unroll
    for (int k = 0; k < 4; ++k) {
        const int tt = t - 3 + k;
        if (tt >= 0) {
            const ushort4 v = *(const ushort4*)&gi[(size_t)(bt - 3 + k) * 4096 + 2048 + h];
            const float a0 = (k == 0) ? w0.x : (k == 1) ? w0.y : (k == 2) ? w0.z : w0.w;
            const float a1 = (k == 0) ? w1.x : (k == 1) ? w1.y : (k == 2) ? w1.z : w1.w;
            const float a2 = (k == 0) ? w2.x : (k == 1) ? w2.y : (k == 2) ? w2.z : w2.w;
            const float a3 = (k == 0) ? w3.x : (k == 1) ? w3.y : (k == 2) ? w3.z : w3.w;
            acc.x += a0 * bf2f(v.x); acc.y += a1 * bf2f(v.y);
            acc.z += a2 * bf2f(v.z); acc.w += a3 * bf2f(v.w);
        }
    }
    ushort4 o;
    o.x = f2bf(acc.x); o.y = f2bf(acc.y); o.z = f2bf(acc.z); o.w = f2bf(acc.w);
    *(ushort4*)&xc[(size_t)bt * 2048 + h] = o;
}

// ---------------------------------------------------------------------------
// scan passes (summaries -> carries -> recompute + gelu fuse)
// ---------------------------------------------------------------------------
__global__ __launch_bounds__(256) void scan1(
    const unsigned short* __restrict__ g, const unsigned short* __restrict__ xc,
    const float* __restrict__ fb, float2* __restrict__ sums)
{
    const int idx = blockIdx.x * 256 + threadIdx.x;   // 2^19
    const int h = idx & (HIDC - 1);
    const int c = (idx >> 11) & (NCHUNK - 1);
    const int b = idx >> 17;

    const float c1 = -8.0f * log1pf(expf(fb[h]));
    float pA = 1.f, hl = 0.f;
    const int row0 = b * TTC + c * CLEN;

    for (int tl = 0; tl < CLEN; ++tl) {
        const size_t row = (size_t)(row0 + tl);
        const float f   = bf2f(g[row * 4096 + h]);
        const float gin = bf2f(g[row * 4096 + 2048 + h]);
        const float xv  = bf2f(xc[row * 2048 + h]);
        const float sf = 1.f / (1.f + expf(-f));
        const float a  = expf(c1 * sf);
        const float be = sqrtf(1.f - a * a + 1e-6f);
        const float si = 1.f / (1.f + expf(-gin));
        hl = a * hl + be * si * xv;
        pA *= a;
    }
    sums[(size_t)(c * BBC + b) * HIDC + h] = make_float2(pA, hl);
}

__global__ __launch_bounds__(256) void scan2(
    const float2* __restrict__ sums, float* __restrict__ carry)
{
    const int idx = blockIdx.x * 256 + threadIdx.x;   // BBC*HIDC = 8192
    const int h = idx & (HIDC - 1), b = idx >> 11;
    float cy = 0.f;
    for (int c = 0; c < NCHUNK; ++c) {
        carry[(size_t)(c * BBC + b) * HIDC + h] = cy;
        const float2 s = sums[(size_t)(c * BBC + b) * HIDC + h];
        cy = s.y + s.x * cy;
    }
}

__global__ __launch_bounds__(256) void scan3(
    unsigned short* __restrict__ gi, const unsigned short* __restrict__ g,
    const unsigned short* __restrict__ xc, const float* __restrict__ fb,
    const float* __restrict__ carry)
{
    const int idx = blockIdx.x * 256 + threadIdx.x;   // 2^19
    const int h = idx & (HIDC - 1);
    const int c = (idx >> 11) & (NCHUNK - 1);
    const int b = idx >> 17;

    const float c1 = -8.0f * log1pf(expf(fb[h]));
    float hh = carry[(size_t)(c * BBC + b) * HIDC + h];
    const int row0 = b * TTC + c * CLEN;

    for (int tl = 0; tl < CLEN; ++tl) {
        const size_t row = (size_t)(row0 + tl);
        const float f    = bf2f(g[row * 4096 + h]);
        const float gin  = bf2f(g[row * 4096 + 2048 + h]);
        const float xv   = bf2f(xc[row * 2048 + h]);
        const float gate = bf2f(gi[row * 4096 + h]);
        const float sf = 1.f / (1.f + expf(-f));
        const float a  = expf(c1 * sf);
        const float be = sqrtf(1.f - a * a + 1e-6f);
        const float si = 1.f / (1.f + expf(-gin));
        hh = a * hh + be * si * xv;
        gi[row * 4096 + h] = f2bf(gelu_exact(gate) * hh);
    }
}

// ---------------------------------------------------------------------------
extern "C" void kernel_launch(void* const* d_in, const int* in_sizes, int n_in,
                              void* d_out, int out_size, void* d_ws, size_t ws_size,
                              hipStream_t stream)
{
    const float* x     = (const float*)d_in[0];
    const float* W_in  = (const float*)d_in[1];
    const float* cw    = (const float*)d_in[2];
    const float* cb    = (const float*)d_in[3];
    const float* W_g   = (const float*)d_in[4];
    const float* b_g   = (const float*)d_in[5];
    const float* fb    = (const float*)d_in[6];
    const float* W_out = (const float*)d_in[7];
    float* out = (float*)d_out;

    const size_t n_gi  = (size_t)BTC * 4096;            // bf16
    const size_t n_g   = (size_t)BTC * 4096;            // bf16
    const size_t n_xc  = (size_t)BTC * 2048;            // bf16
    const size_t n_sum = (size_t)NCHUNK * BBC * HIDC;   // float2 / float
    const size_t nX    = (size_t)BTC * DIMC;            // x_bf (aliases g)
    const size_t nWin  = (size_t)4096 * 1024;           // (aliases g)
    const size_t nWg   = (size_t)4096 * 2048;
    const size_t nWout = (size_t)1024 * 2048;

    const size_t need_base = (n_gi + n_g + n_xc) * 2 + n_sum * 12;     // 166 MiB
    const size_t need_full = need_base + (nWg + nWout) * 2;            // 186 MiB
    if (ws_size < need_base) return;
    const bool use8 = (ws_size >= need_full);

    unsigned short* gi = (unsigned short*)d_ws;
    unsigned short* g  = gi + n_gi;
    unsigned short* xc = g + n_g;
    float2* sums  = (float2*)(xc + n_xc);
    float*  carry = (float*)(sums + n_sum);
    unsigned short* wg_bf   = (unsigned short*)(carry + n_sum);
    unsigned short* wout_bf = wg_bf + nWg;
    // x_bf and win_bf alias g (dead until GEMM2 writes it)
    unsigned short* x_bf   = g;
    unsigned short* win_bf = g + nX;

    if (use8) {
        cvt_bf16<<<(int)(nX    / 8 / 256), 256, 0, stream>>>(x,     x_bf,    (int)(nX    / 8));
        cvt_bf16<<<(int)(nWin  / 8 / 256), 256, 0, stream>>>(W_in,  win_bf,  (int)(nWin  / 8));
        cvt_bf16<<<(int)(nWg   / 8 / 256), 256, 0, stream>>>(W_g,   wg_bf,   (int)(nWg   / 8));
        cvt_bf16<<<(int)(nWout / 8 / 256), 256, 0, stream>>>(W_out, wout_bf, (int)(nWout / 8));

        // GEMM1: gi = x @ W_in^T        M=8192 N=4096 K=1024
        gemm8p<unsigned short, 0><<<dim3(4096 / 256, BTC / 256), 512, 0, stream>>>(
            x_bf, DIMC, win_bf, DIMC, gi, 4096, nullptr, DIMC);

        conv_k<<<(BTC * 512) / 256, 256, 0, stream>>>(gi, cw, cb, xc);

        // GEMM2: g = xc @ W_g^T + b_g   M=8192 N=4096 K=2048
        gemm8p<unsigned short, 1><<<dim3(4096 / 256, BTC / 256), 512, 0, stream>>>(
            xc, HIDC, wg_bf, HIDC, g, 4096, b_g, HIDC);

        scan1<<<(BBC * NCHUNK * HIDC) / 256, 256, 0, stream>>>(g, xc, fb, sums);
        scan2<<<(BBC * HIDC) / 256, 256, 0, stream>>>(sums, carry);
        scan3<<<(BBC * NCHUNK * HIDC) / 256, 256, 0, stream>>>(gi, g, xc, fb, carry);

        // GEMM3: out = u @ W_out^T      M=8192 N=1024 K=2048 (u in gi cols 0..2047)
        gemm8p<float, 0><<<dim3(DIMC / 256, BTC / 256), 512, 0, stream>>>(
            gi, 4096, wout_bf, HIDC, out, DIMC, nullptr, HIDC);
    } else {
        gemm_bt<float, float, unsigned short, 0>
            <<<dim3(4096 / 128, BTC / 128), 256, 0, stream>>>(
            x, DIMC, W_in, DIMC, gi, 4096, nullptr, DIMC);
        conv_k<<<(BTC * 512) / 256, 256, 0, stream>>>(gi, cw, cb, xc);
        gemm_bt<unsigned short, float, unsigned short, 1>
            <<<dim3(4096 / 128, BTC / 128), 256, 0, stream>>>(
            xc, HIDC, W_g, HIDC, g, 4096, b_g, HIDC);
        scan1<<<(BBC * NCHUNK * HIDC) / 256, 256, 0, stream>>>(g, xc, fb, sums);
        scan2<<<(BBC * HIDC) / 256, 256, 0, stream>>>(sums, carry);
        scan3<<<(BBC * NCHUNK * HIDC) / 256, 256, 0, stream>>>(gi, g, xc, fb, carry);
        gemm_bt<unsigned short, float, float, 0>
            <<<dim3(DIMC / 128, BTC / 128), 256, 0, stream>>>(
            gi, 4096, W_out, HIDC, out, DIMC, nullptr, HIDC);
    }
}

// Round 5
// 413.699 us; speedup vs baseline: 1.4836x; 1.0525x over previous
//
#include <hip/hip_runtime.h>
#include <hip/hip_bf16.h>
#include <math.h>

// RG-LRU block: GEMM1 -> depthwise causal conv -> GEMM2 -> chunked linear scan -> GEMM3
// GEMMs: 256x256 4-phase (gemm8p) / 128x256 2-phase 3-buffer (gemm3p) bf16 MFMA kernels.
// Per-phase single-half-tile consumption + distributed counted vmcnt (T3/T4),
// XOR-swizzled LDS via pre-swizzled global source (T2), setprio (T5), XCD swizzle (T1).

#define HIDC 2048
#define DIMC 1024
#define BBC 4
#define TTC 2048
#define BTC (BBC*TTC)      // 8192 rows
#define NCHUNK 64
#define CLEN 32            // TTC / NCHUNK

typedef __attribute__((ext_vector_type(8))) short bfx8;
typedef __attribute__((ext_vector_type(4))) float f32x4;

__device__ __forceinline__ unsigned short f2bf(float f) {
    return __builtin_bit_cast(unsigned short, __float2bfloat16(f));
}
__device__ __forceinline__ float bf2f(unsigned short u) {
    union { unsigned int i; float f; } v; v.i = ((unsigned)u) << 16; return v.f;
}
__device__ __forceinline__ float gelu_exact(float x) {
    return 0.5f * x * (1.0f + erff(x * 0.70710678118654752f));
}

typedef const unsigned int __attribute__((address_space(1)))* gas_ptr;
typedef unsigned int __attribute__((address_space(3)))* las_ptr;
__device__ __forceinline__ void gload_lds16(const void* g, void* l) {
    __builtin_amdgcn_global_load_lds((gas_ptr)g, (las_ptr)l, 16, 0, 0);
}

// Stage one 128-row x 64-col bf16 half-tile: 8 waves x 2 gloads x 8 rows.
// LDS dest linear; global source col pre-swizzled (granule ^= row&7)  [rule #21]
__device__ __forceinline__ void stage_half(
    const unsigned short* __restrict__ gsrc,  // pre-offset: +grow rows, +gswz cols
    int ld, unsigned short* ldsdst, int wave)
{
    #pragma unroll
    for (int j = 0; j < 2; ++j) {
        const int r0 = (wave * 2 + j) * 8;
        gload_lds16(gsrc + (size_t)r0 * ld, ldsdst + r0 * 64);
    }
}

#define SBAR()  __builtin_amdgcn_sched_barrier(0)
#define BAR()   do { SBAR(); __builtin_amdgcn_s_barrier(); SBAR(); } while (0)

// ===========================================================================
// gemm8p: 256x256 tile, BK=64, 8 waves, 4 phases/K-tile.
// Phase p covers quadrant (A-half a_p, B-half b_p): (0,0),(0,1),(1,1),(1,0).
// Stage t+1 halves: A0@p0, B0@p1, B1@p2, A1@p3. Waits (steady): vmcnt(4) at
// p0/p1/p3; none at p2. Queue invariant at tile start: [t:B1, t:A1] (4 loads).
// Tail tile: vmcnt(2)@p0, vmcnt(0)@p1.
// ===========================================================================
template<typename TC, int BIAS>
__global__ __launch_bounds__(512, 2) void gemm8p(
    const unsigned short* __restrict__ A, int lda,
    const unsigned short* __restrict__ Bm, int ldb,
    TC* __restrict__ C, int ldc,
    const float* __restrict__ bias, int K, int gridN, int q8)
{
    __shared__ __align__(16) unsigned short lds[2][2][256 * 64]; // [buf][A/B]

    const int tid  = threadIdx.x;
    const int lin  = blockIdx.x;
    const int swz  = (lin & 7) * q8 + (lin >> 3);      // XCD swizzle (nwg%8==0)
    const int bm   = swz / gridN, bn = swz % gridN;

    const int wave = tid >> 6, lane = tid & 63;
    const int wm   = wave >> 2, wn = wave & 3;          // 64-row / 32-col group in quadrant
    const int lrow = lane & 15, lq = lane >> 4;

    const int key = (lrow & 7) << 3;
    const int e0  = (lq << 3) ^ key;
    const int e1  = e0 ^ 32;
    const int aRow = (wm * 64 + lrow) * 64;
    const int bRow = (wn * 32 + lrow) * 64;

    const int grow = lane >> 3;
    const int gswz = ((lane & 7) ^ (grow & 7)) << 3;
    const unsigned short* aS = A  + (size_t)(bm * 256 + grow) * lda + gswz;
    const unsigned short* bS = Bm + (size_t)(bn * 256 + grow) * ldb + gswz;

    f32x4 acc[8][4];
    #pragma unroll
    for (int i = 0; i < 8; ++i)
        #pragma unroll
        for (int n = 0; n < 4; ++n)
            acc[i][n] = (f32x4){0.f, 0.f, 0.f, 0.f};

    bfx8 areg[4][2], b0r[2][2], b1r[2][2];
    const int NT = K >> 6;

    // prologue: tile0 halves in order A0,B0,B1,A1; wait A0,B0 landed
    stage_half(aS,                     lda, &lds[0][0][0],        wave);
    stage_half(bS,                     ldb, &lds[0][1][0],        wave);
    stage_half(bS + (size_t)128 * ldb, ldb, &lds[0][1][128 * 64], wave);
    stage_half(aS + (size_t)128 * lda, lda, &lds[0][0][128 * 64], wave);
    asm volatile("s_waitcnt vmcnt(4)" ::: "memory");
    BAR();

    for (int t = 0; t < NT; ++t) {
        const int cur = t & 1, nxt = cur ^ 1;
        const unsigned short* Ac = lds[cur][0];
        const unsigned short* Bc = lds[cur][1];
        const bool hn = (t + 1 < NT);
        const int k1 = (t + 1) << 6;

        // ---- p0: quad (A0,B0); reads A0-sub + B0-sub; stage t+1:A0
        #pragma unroll
        for (int i = 0; i < 4; ++i) {
            areg[i][0] = *(const bfx8*)(Ac + aRow + i * 1024 + e0);
            areg[i][1] = *(const bfx8*)(Ac + aRow + i * 1024 + e1);
        }
        #pragma unroll
        for (int n = 0; n < 2; ++n) {
            b0r[n][0] = *(const bfx8*)(Bc + bRow + n * 1024 + e0);
            b0r[n][1] = *(const bfx8*)(Bc + bRow + n * 1024 + e1);
        }
        if (hn) { stage_half(aS + k1, lda, &lds[nxt][0][0], wave);
                  asm volatile("s_waitcnt vmcnt(4)" ::: "memory"); }
        else    { asm volatile("s_waitcnt vmcnt(2)" ::: "memory"); }
        BAR();
        __builtin_amdgcn_s_setprio(1);
        #pragma unroll
        for (int i = 0; i < 4; ++i)
            #pragma unroll
            for (int n = 0; n < 2; ++n)
                #pragma unroll
                for (int kk = 0; kk < 2; ++kk)
                    acc[i][n] = __builtin_amdgcn_mfma_f32_16x16x32_bf16(areg[i][kk], b0r[n][kk], acc[i][n], 0, 0, 0);
        __builtin_amdgcn_s_setprio(0);
        BAR();

        // ---- p1: quad (A0,B1); reads B1-sub; stage t+1:B0
        #pragma unroll
        for (int n = 0; n < 2; ++n) {
            b1r[n][0] = *(const bfx8*)(Bc + 128 * 64 + bRow + n * 1024 + e0);
            b1r[n][1] = *(const bfx8*)(Bc + 128 * 64 + bRow + n * 1024 + e1);
        }
        if (hn) { stage_half(bS + k1, ldb, &lds[nxt][1][0], wave);
                  asm volatile("s_waitcnt vmcnt(4)" ::: "memory"); }
        else    { asm volatile("s_waitcnt vmcnt(0)" ::: "memory"); }
        BAR();
        __builtin_amdgcn_s_setprio(1);
        #pragma unroll
        for (int i = 0; i < 4; ++i)
            #pragma unroll
            for (int n = 0; n < 2; ++n)
                #pragma unroll
                for (int kk = 0; kk < 2; ++kk)
                    acc[i][2 + n] = __builtin_amdgcn_mfma_f32_16x16x32_bf16(areg[i][kk], b1r[n][kk], acc[i][2 + n], 0, 0, 0);
        __builtin_amdgcn_s_setprio(0);
        BAR();

        // ---- p2: quad (A1,B1); reads A1-sub; stage t+1:B1; no wait
        #pragma unroll
        for (int i = 0; i < 4; ++i) {
            areg[i][0] = *(const bfx8*)(Ac + 128 * 64 + aRow + i * 1024 + e0);
            areg[i][1] = *(const bfx8*)(Ac + 128 * 64 + aRow + i * 1024 + e1);
        }
        if (hn) stage_half(bS + (size_t)128 * ldb + k1, ldb, &lds[nxt][1][128 * 64], wave);
        BAR();
        __builtin_amdgcn_s_setprio(1);
        #pragma unroll
        for (int i = 0; i < 4; ++i)
            #pragma unroll
            for (int n = 0; n < 2; ++n)
                #pragma unroll
                for (int kk = 0; kk < 2; ++kk)
                    acc[4 + i][2 + n] = __builtin_amdgcn_mfma_f32_16x16x32_bf16(areg[i][kk], b1r[n][kk], acc[4 + i][2 + n], 0, 0, 0);
        __builtin_amdgcn_s_setprio(0);
        BAR();

        // ---- p3: quad (A1,B0); b0r still live (no reads); stage t+1:A1
        if (hn) { stage_half(aS + (size_t)128 * lda + k1, lda, &lds[nxt][0][128 * 64], wave);
                  asm volatile("s_waitcnt vmcnt(4)" ::: "memory"); }
        BAR();
        __builtin_amdgcn_s_setprio(1);
        #pragma unroll
        for (int i = 0; i < 4; ++i)
            #pragma unroll
            for (int n = 0; n < 2; ++n)
                #pragma unroll
                for (int kk = 0; kk < 2; ++kk)
                    acc[4 + i][n] = __builtin_amdgcn_mfma_f32_16x16x32_bf16(areg[i][kk], b0r[n][kk], acc[4 + i][n], 0, 0, 0);
        __builtin_amdgcn_s_setprio(0);
        BAR();
    }

    // epilogue: C/D layout col=lane&15, row=(lane>>4)*4+reg
    #pragma unroll
    for (int ai = 0; ai < 8; ++ai) {
        const int a = ai >> 2, i = ai & 3;
        const int row0 = bm * 256 + a * 128 + wm * 64 + i * 16 + lq * 4;
        #pragma unroll
        for (int c = 0; c < 4; ++c) {
            const int col = bn * 256 + (c >> 1) * 128 + wn * 32 + (c & 1) * 16 + lrow;
            float bv = 0.f;
            if (BIAS) bv = bias[col];
            #pragma unroll
            for (int r = 0; r < 4; ++r) {
                const float v = acc[ai][c][r] + bv;
                if constexpr (sizeof(TC) == 2)
                    C[(size_t)(row0 + r) * ldc + col] = (TC)f2bf(v);
                else
                    C[(size_t)(row0 + r) * ldc + col] = (TC)v;
            }
        }
    }
}

// ===========================================================================
// gemm3p: 128x256 tile, BK=64, 8 waves, 2 phases/K-tile, 3-buffer LDS,
// prefetch 2 tiles ahead. Stage t+2: {A,B0}@p0, B1@p1.
// Waits: steady vmcnt(10)@p0, vmcnt(8)@p1; t=NT-2: 6/2; t=NT-1: 0/-.
// ===========================================================================
template<typename TC>
__global__ __launch_bounds__(512, 2) void gemm3p(
    const unsigned short* __restrict__ A, int lda,
    const unsigned short* __restrict__ Bm, int ldb,
    TC* __restrict__ C, int ldc, int K, int gridN, int q8)
{
    __shared__ __align__(16) unsigned short lds[3][3 * 128 * 64]; // [buf][A|B0|B1] 144 KiB

    const int tid  = threadIdx.x;
    const int lin  = blockIdx.x;
    const int swz  = (lin & 7) * q8 + (lin >> 3);
    const int bm   = swz / gridN, bn = swz % gridN;

    const int wave = tid >> 6, lane = tid & 63;
    const int wm   = wave >> 2, wn = wave & 3;
    const int lrow = lane & 15, lq = lane >> 4;

    const int key = (lrow & 7) << 3;
    const int e0  = (lq << 3) ^ key;
    const int e1  = e0 ^ 32;
    const int aRow = (wm * 64 + lrow) * 64;
    const int bRow = (wn * 32 + lrow) * 64;

    const int grow = lane >> 3;
    const int gswz = ((lane & 7) ^ (grow & 7)) << 3;
    const unsigned short* aS = A  + (size_t)(bm * 128 + grow) * lda + gswz;
    const unsigned short* bS = Bm + (size_t)(bn * 256 + grow) * ldb + gswz;

    f32x4 acc[4][4];
    #pragma unroll
    for (int i = 0; i < 4; ++i)
        #pragma unroll
        for (int n = 0; n < 4; ++n)
            acc[i][n] = (f32x4){0.f, 0.f, 0.f, 0.f};

    bfx8 areg[4][2], br[2][2];
    const int NT = K >> 6;

    // prologue: t0 -> buf0, t1 -> buf1 (order A,B0,B1 each); wait t0:{A,B0}
    stage_half(aS,                          lda, &lds[0][0],     wave);
    stage_half(bS,                          ldb, &lds[0][8192],  wave);
    stage_half(bS + (size_t)128 * ldb,      ldb, &lds[0][16384], wave);
    stage_half(aS + 64,                     lda, &lds[1][0],     wave);
    stage_half(bS + 64,                     ldb, &lds[1][8192],  wave);
    stage_half(bS + (size_t)128 * ldb + 64, ldb, &lds[1][16384], wave);
    asm volatile("s_waitcnt vmcnt(8)" ::: "memory");
    BAR();

    int cur = 0;
    for (int t = 0; t < NT; ++t) {
        const unsigned short* L = lds[cur];
        int nx2 = cur + 2; if (nx2 >= 3) nx2 -= 3;
        const bool h2 = (t + 2 < NT);
        const int k2 = (t + 2) << 6;

        // ---- p0: reads A + B0; stage t+2:{A,B0}
        #pragma unroll
        for (int i = 0; i < 4; ++i) {
            areg[i][0] = *(const bfx8*)(L + aRow + i * 1024 + e0);
            areg[i][1] = *(const bfx8*)(L + aRow + i * 1024 + e1);
        }
        #pragma unroll
        for (int n = 0; n < 2; ++n) {
            br[n][0] = *(const bfx8*)(L + 8192 + bRow + n * 1024 + e0);
            br[n][1] = *(const bfx8*)(L + 8192 + bRow + n * 1024 + e1);
        }
        if (h2) {
            stage_half(aS + k2, lda, &lds[nx2][0],    wave);
            stage_half(bS + k2, ldb, &lds[nx2][8192], wave);
            asm volatile("s_waitcnt vmcnt(10)" ::: "memory");
        } else if (t + 1 < NT) {
            asm volatile("s_waitcnt vmcnt(6)" ::: "memory");
        } else {
            asm volatile("s_waitcnt vmcnt(0)" ::: "memory");
        }
        BAR();
        __builtin_amdgcn_s_setprio(1);
        #pragma unroll
        for (int i = 0; i < 4; ++i)
            #pragma unroll
            for (int n = 0; n < 2; ++n)
                #pragma unroll
                for (int kk = 0; kk < 2; ++kk)
                    acc[i][n] = __builtin_amdgcn_mfma_f32_16x16x32_bf16(areg[i][kk], br[n][kk], acc[i][n], 0, 0, 0);
        __builtin_amdgcn_s_setprio(0);
        BAR();

        // ---- p1: reads B1 (A regs reused); stage t+2:B1
        #pragma unroll
        for (int n = 0; n < 2; ++n) {
            br[n][0] = *(const bfx8*)(L + 16384 + bRow + n * 1024 + e0);
            br[n][1] = *(const bfx8*)(L + 16384 + bRow + n * 1024 + e1);
        }
        if (h2) {
            stage_half(bS + (size_t)128 * ldb + k2, ldb, &lds[nx2][16384], wave);
            asm volatile("s_waitcnt vmcnt(8)" ::: "memory");
        } else if (t + 1 < NT) {
            asm volatile("s_waitcnt vmcnt(2)" ::: "memory");
        }
        BAR();
        __builtin_amdgcn_s_setprio(1);
        #pragma unroll
        for (int i = 0; i < 4; ++i)
            #pragma unroll
            for (int n = 0; n < 2; ++n)
                #pragma unroll
                for (int kk = 0; kk < 2; ++kk)
                    acc[i][2 + n] = __builtin_amdgcn_mfma_f32_16x16x32_bf16(areg[i][kk], br[n][kk], acc[i][2 + n], 0, 0, 0);
        __builtin_amdgcn_s_setprio(0);
        BAR();

        cur = (cur + 1 == 3) ? 0 : cur + 1;
    }

    #pragma unroll
    for (int i = 0; i < 4; ++i) {
        const int row0 = bm * 128 + wm * 64 + i * 16 + lq * 4;
        #pragma unroll
        for (int c = 0; c < 4; ++c) {
            const int col = bn * 256 + (c >> 1) * 128 + wn * 32 + (c & 1) * 16 + lrow;
            #pragma unroll
            for (int r = 0; r < 4; ++r) {
                const float v = acc[i][c][r];
                if constexpr (sizeof(TC) == 2)
                    C[(size_t)(row0 + r) * ldc + col] = (TC)f2bf(v);
                else
                    C[(size_t)(row0 + r) * ldc + col] = (TC)v;
            }
        }
    }
}

// ===========================================================================
// Fallback 128x128 GEMM (round-3 proven) for small workspace
// ===========================================================================
template<typename T>
__device__ __forceinline__ void stage_op(const T* __restrict__ base, int ld, int k0,
                                         unsigned short* lds_, int tid)
{
    if constexpr (sizeof(T) == 2) {
        const int wave = tid >> 6, lane = tid & 63;
        const int grow = lane >> 3;
        const int gcol = (lane & 7) << 3;
        #pragma unroll
        for (int j = 0; j < 4; ++j) {
            const int r0 = wave * 32 + j * 8;
            gload_lds16((const unsigned short*)base + (size_t)(r0 + grow) * ld + k0 + gcol,
                        &lds_[r0 * 64]);
        }
    } else {
        const int srow = tid >> 4, scol = (tid & 15) << 2;
        #pragma unroll
        for (int p = 0; p < 8; ++p) {
            const int r = p * 16 + srow;
            const float4 v = *(const float4*)((const float*)base + (size_t)r * ld + k0 + scol);
            uint2 w;
            w.x = (unsigned)f2bf(v.x) | ((unsigned)f2bf(v.y) << 16);
            w.y = (unsigned)f2bf(v.z) | ((unsigned)f2bf(v.w) << 16);
            *(uint2*)&lds_[r * 64 + scol] = w;
        }
    }
}

template<typename TA, typename TB, typename TC, int BIAS>
__global__ __launch_bounds__(256) void gemm_bt(
    const TA* __restrict__ A, int lda,
    const TB* __restrict__ Bm, int ldb,
    TC* __restrict__ C, int ldc,
    const float* __restrict__ bias, int K)
{
    __shared__ __align__(16) unsigned short As[128 * 64];
    __shared__ __align__(16) unsigned short Bs[128 * 64];

    const int tid  = threadIdx.x;
    const int bm   = blockIdx.y, bn = blockIdx.x;
    const int wave = tid >> 6,  lane = tid & 63;
    const int wm   = wave >> 1, wn = wave & 1;
    const int lrow = lane & 15, lq = lane >> 4;

    f32x4 acc[4][4];
    #pragma unroll
    for (int i = 0; i < 4; ++i)
        #pragma unroll
        for (int j = 0; j < 4; ++j)
            acc[i][j] = (f32x4){0.f, 0.f, 0.f, 0.f};

    const TA* Abase = A  + (size_t)(bm * 128) * lda;
    const TB* Bbase = Bm + (size_t)(bn * 128) * ldb;

    for (int k0 = 0; k0 < K; k0 += 64) {
        stage_op<TA>(Abase, lda, k0, As, tid);
        stage_op<TB>(Bbase, ldb, k0, Bs, tid);
        __syncthreads();
        #pragma unroll
        for (int kk = 0; kk < 2; ++kk) {
            bfx8 af[4], bfr[4];
            const int kb = kk * 32 + lq * 8;
            #pragma unroll
            for (int m = 0; m < 4; ++m)
                af[m] = *(const bfx8*)&As[(wm * 64 + m * 16 + lrow) * 64 + kb];
            #pragma unroll
            for (int n = 0; n < 4; ++n)
                bfr[n] = *(const bfx8*)&Bs[(wn * 64 + n * 16 + lrow) * 64 + kb];
            #pragma unroll
            for (int m = 0; m < 4; ++m)
                #pragma unroll
                for (int n = 0; n < 4; ++n)
                    acc[m][n] = __builtin_amdgcn_mfma_f32_16x16x32_bf16(af[m], bfr[n], acc[m][n], 0, 0, 0);
        }
        __syncthreads();
    }

    #pragma unroll
    for (int m = 0; m < 4; ++m) {
        #pragma unroll
        for (int n = 0; n < 4; ++n) {
            const int row0 = bm * 128 + wm * 64 + m * 16 + lq * 4;
            const int col  = bn * 128 + wn * 64 + n * 16 + lrow;
            float bv = 0.f;
            if (BIAS) bv = bias[col];
            #pragma unroll
            for (int r = 0; r < 4; ++r) {
                const float v = acc[m][n][r] + bv;
                if constexpr (sizeof(TC) == 2)
                    C[(size_t)(row0 + r) * ldc + col] = (TC)f2bf(v);
                else
                    C[(size_t)(row0 + r) * ldc + col] = (TC)v;
            }
        }
    }
}

// ---------------------------------------------------------------------------
__global__ __launch_bounds__(256) void cvt_bf16(
    const float* __restrict__ in, unsigned short* __restrict__ out, int n8)
{
    const int i = blockIdx.x * 256 + threadIdx.x;
    if (i >= n8) return;
    const float4 a = ((const float4*)in)[i * 2];
    const float4 b = ((const float4*)in)[i * 2 + 1];
    uint4 w;
    w.x = (unsigned)f2bf(a.x) | ((unsigned)f2bf(a.y) << 16);
    w.y = (unsigned)f2bf(a.z) | ((unsigned)f2bf(a.w) << 16);
    w.z = (unsigned)f2bf(b.x) | ((unsigned)f2bf(b.y) << 16);
    w.w = (unsigned)f2bf(b.z) | ((unsigned)f2bf(b.w) << 16);
    ((uint4*)out)[i] = w;
}

// ---------------------------------------------------------------------------
__global__ __launch_bounds__(256) void conv_k(
    const unsigned short* __restrict__ gi, const float* __restrict__ w,
    const float* __restrict__ cb, unsigned short* __restrict__ xc)
{
    const int idx = blockIdx.x * 256 + threadIdx.x;   // BTC*512
    const int h4 = idx & 511, bt = idx >> 9;
    const int h = h4 << 2;
    const int t = bt & (TTC - 1);

    float4 acc = *(const float4*)&cb[h];
    const float4 w0 = *(const float4*)&w[(h + 0) * 4];
    const float4 w1 = *(const float4*)&w[(h + 1) * 4];
    const float4 w2 = *(const float4*)&w[(h + 2) * 4];
    const float4 w3 = *(const float4*)&w[(h + 3) * 4];

    #pragma unroll
    for (int k = 0; k < 4; ++k) {
        const int tt = t - 3 + k;
        if (tt >= 0) {
            const ushort4 v = *(const ushort4*)&gi[(size_t)(bt - 3 + k) * 4096 + 2048 + h];
            const float a0 = (k == 0) ? w0.x : (k == 1) ? w0.y : (k == 2) ? w0.z : w0.w;
            const float a1 = (k == 0) ? w1.x : (k == 1) ? w1.y : (k == 2) ? w1.z : w1.w;
            const float a2 = (k == 0) ? w2.x : (k == 1) ? w2.y : (k == 2) ? w2.z : w2.w;
            const float a3 = (k == 0) ? w3.x : (k == 1) ? w3.y : (k == 2) ? w3.z : w3.w;
            acc.x += a0 * bf2f(v.x); acc.y += a1 * bf2f(v.y);
            acc.z += a2 * bf2f(v.z); acc.w += a3 * bf2f(v.w);
        }
    }
    ushort4 o;
    o.x = f2bf(acc.x); o.y = f2bf(acc.y); o.z = f2bf(acc.z); o.w = f2bf(acc.w);
    *(ushort4*)&xc[(size_t)bt * 2048 + h] = o;
}

// ---------------------------------------------------------------------------
__global__ __launch_bounds__(256) void scan1(
    const unsigned short* __restrict__ g, const unsigned short* __restrict__ xc,
    const float* __restrict__ fb, float2* __restrict__ sums)
{
    const int idx = blockIdx.x * 256 + threadIdx.x;   // 2^19
    const int h = idx & (HIDC - 1);
    const int c = (idx >> 11) & (NCHUNK - 1);
    const int b = idx >> 17;

    const float c1 = -8.0f * log1pf(expf(fb[h]));
    float pA = 1.f, hl = 0.f;
    const int row0 = b * TTC + c * CLEN;

    for (int tl = 0; tl < CLEN; ++tl) {
        const size_t row = (size_t)(row0 + tl);
        const float f   = bf2f(g[row * 4096 + h]);
        const float gin = bf2f(g[row * 4096 + 2048 + h]);
        const float xv  = bf2f(xc[row * 2048 + h]);
        const float sf = 1.f / (1.f + expf(-f));
        const float a  = expf(c1 * sf);
        const float be = sqrtf(1.f - a * a + 1e-6f);
        const float si = 1.f / (1.f + expf(-gin));
        hl = a * hl + be * si * xv;
        pA *= a;
    }
    sums[(size_t)(c * BBC + b) * HIDC + h] = make_float2(pA, hl);
}

__global__ __launch_bounds__(256) void scan2(
    const float2* __restrict__ sums, float* __restrict__ carry)
{
    const int idx = blockIdx.x * 256 + threadIdx.x;   // BBC*HIDC = 8192
    const int h = idx & (HIDC - 1), b = idx >> 11;
    float cy = 0.f;
    for (int c = 0; c < NCHUNK; ++c) {
        carry[(size_t)(c * BBC + b) * HIDC + h] = cy;
        const float2 s = sums[(size_t)(c * BBC + b) * HIDC + h];
        cy = s.y + s.x * cy;
    }
}

__global__ __launch_bounds__(256) void scan3(
    unsigned short* __restrict__ gi, const unsigned short* __restrict__ g,
    const unsigned short* __restrict__ xc, const float* __restrict__ fb,
    const float* __restrict__ carry)
{
    const int idx = blockIdx.x * 256 + threadIdx.x;   // 2^19
    const int h = idx & (HIDC - 1);
    const int c = (idx >> 11) & (NCHUNK - 1);
    const int b = idx >> 17;

    const float c1 = -8.0f * log1pf(expf(fb[h]));
    float hh = carry[(size_t)(c * BBC + b) * HIDC + h];
    const int row0 = b * TTC + c * CLEN;

    for (int tl = 0; tl < CLEN; ++tl) {
        const size_t row = (size_t)(row0 + tl);
        const float f    = bf2f(g[row * 4096 + h]);
        const float gin  = bf2f(g[row * 4096 + 2048 + h]);
        const float xv   = bf2f(xc[row * 2048 + h]);
        const float gate = bf2f(gi[row * 4096 + h]);
        const float sf = 1.f / (1.f + expf(-f));
        const float a  = expf(c1 * sf);
        const float be = sqrtf(1.f - a * a + 1e-6f);
        const float si = 1.f / (1.f + expf(-gin));
        hh = a * hh + be * si * xv;
        gi[row * 4096 + h] = f2bf(gelu_exact(gate) * hh);
    }
}

// ---------------------------------------------------------------------------
extern "C" void kernel_launch(void* const* d_in, const int* in_sizes, int n_in,
                              void* d_out, int out_size, void* d_ws, size_t ws_size,
                              hipStream_t stream)
{
    const float* x     = (const float*)d_in[0];
    const float* W_in  = (const float*)d_in[1];
    const float* cw    = (const float*)d_in[2];
    const float* cb    = (const float*)d_in[3];
    const float* W_g   = (const float*)d_in[4];
    const float* b_g   = (const float*)d_in[5];
    const float* fb    = (const float*)d_in[6];
    const float* W_out = (const float*)d_in[7];
    float* out = (float*)d_out;

    const size_t n_gi  = (size_t)BTC * 4096;            // bf16
    const size_t n_g   = (size_t)BTC * 4096;            // bf16
    const size_t n_xc  = (size_t)BTC * 2048;            // bf16
    const size_t n_sum = (size_t)NCHUNK * BBC * HIDC;   // float2 / float
    const size_t nX    = (size_t)BTC * DIMC;            // x_bf (aliases g)
    const size_t nWin  = (size_t)4096 * 1024;           // (aliases g)
    const size_t nWg   = (size_t)4096 * 2048;
    const size_t nWout = (size_t)1024 * 2048;

    const size_t need_base = (n_gi + n_g + n_xc) * 2 + n_sum * 12;     // 166 MiB
    const size_t need_full = need_base + (nWg + nWout) * 2;            // 186 MiB
    if (ws_size < need_base) return;
    const bool use8 = (ws_size >= need_full);

    unsigned short* gi = (unsigned short*)d_ws;
    unsigned short* g  = gi + n_gi;
    unsigned short* xc = g + n_g;
    float2* sums  = (float2*)(xc + n_xc);
    float*  carry = (float*)(sums + n_sum);
    unsigned short* wg_bf   = (unsigned short*)(carry + n_sum);
    unsigned short* wout_bf = wg_bf + nWg;
    unsigned short* x_bf   = g;            // aliases g (dead until GEMM2)
    unsigned short* win_bf = g + nX;

    if (use8) {
        cvt_bf16<<<(int)(nX    / 8 / 256), 256, 0, stream>>>(x,     x_bf,    (int)(nX    / 8));
        cvt_bf16<<<(int)(nWin  / 8 / 256), 256, 0, stream>>>(W_in,  win_bf,  (int)(nWin  / 8));
        cvt_bf16<<<(int)(nWg   / 8 / 256), 256, 0, stream>>>(W_g,   wg_bf,   (int)(nWg   / 8));
        cvt_bf16<<<(int)(nWout / 8 / 256), 256, 0, stream>>>(W_out, wout_bf, (int)(nWout / 8));

        // GEMM1: gi = x @ W_in^T        M=8192 N=4096 K=1024   nwg=512
        gemm8p<unsigned short, 0><<<512, 512, 0, stream>>>(
            x_bf, DIMC, win_bf, DIMC, gi, 4096, nullptr, DIMC, 16, 64);

        conv_k<<<(BTC * 512) / 256, 256, 0, stream>>>(gi, cw, cb, xc);

        // GEMM2: g = xc @ W_g^T + b_g   M=8192 N=4096 K=2048   nwg=512
        gemm8p<unsigned short, 1><<<512, 512, 0, stream>>>(
            xc, HIDC, wg_bf, HIDC, g, 4096, b_g, HIDC, 16, 64);

        scan1<<<(BBC * NCHUNK * HIDC) / 256, 256, 0, stream>>>(g, xc, fb, sums);
        scan2<<<(BBC * HIDC) / 256, 256, 0, stream>>>(sums, carry);
        scan3<<<(BBC * NCHUNK * HIDC) / 256, 256, 0, stream>>>(gi, g, xc, fb, carry);

        // GEMM3: out = u @ W_out^T      M=8192 N=1024 K=2048   nwg=256 (128x256 tiles)
        gemm3p<float><<<256, 512, 0, stream>>>(
            gi, 4096, wout_bf, HIDC, out, DIMC, HIDC, 4, 32);
    } else {
        gemm_bt<float, float, unsigned short, 0>
            <<<dim3(4096 / 128, BTC / 128), 256, 0, stream>>>(
            x, DIMC, W_in, DIMC, gi, 4096, nullptr, DIMC);
        conv_k<<<(BTC * 512) / 256, 256, 0, stream>>>(gi, cw, cb, xc);
        gemm_bt<unsigned short, float, unsigned short, 1>
            <<<dim3(4096 / 128, BTC / 128), 256, 0, stream>>>(
            xc, HIDC, W_g, HIDC, g, 4096, b_g, HIDC);
        scan1<<<(BBC * NCHUNK * HIDC) / 256, 256, 0, stream>>>(g, xc, fb, sums);
        scan2<<<(BBC * HIDC) / 256, 256, 0, stream>>>(sums, carry);
        scan3<<<(BBC * NCHUNK * HIDC) / 256, 256, 0, stream>>>(gi, g, xc, fb, carry);
        gemm_bt<unsigned short, float, float, 0>
            <<<dim3(DIMC / 128, BTC / 128), 256, 0, stream>>>(
            gi, 4096, W_out, HIDC, out, DIMC, nullptr, HIDC);
    }
}

// Round 6
// 413.676 us; speedup vs baseline: 1.4837x; 1.0001x over previous
//
#include <hip/hip_runtime.h>
#include <hip/hip_bf16.h>
#include <math.h>

// RG-LRU block: GEMM1 -> depthwise causal conv -> GEMM2 -> chunked linear scan -> GEMM3
// gemm8p: 256x256 4-phase schedule with post-MFMA ds_read prefetch (LDS-drain/MFMA overlap).
// T1 XCD swizzle, T2 XOR-swizzled LDS via pre-swizzled global source, T4 counted vmcnt, T5 setprio.

#define HIDC 2048
#define DIMC 1024
#define BBC 4
#define TTC 2048
#define BTC (BBC*TTC)      // 8192 rows
#define NCHUNK 64
#define CLEN 32            // TTC / NCHUNK

typedef __attribute__((ext_vector_type(8))) short bfx8;
typedef __attribute__((ext_vector_type(4))) float f32x4;

__device__ __forceinline__ unsigned short f2bf(float f) {
    return __builtin_bit_cast(unsigned short, __float2bfloat16(f));
}
__device__ __forceinline__ float bf2f(unsigned short u) {
    union { unsigned int i; float f; } v; v.i = ((unsigned)u) << 16; return v.f;
}
__device__ __forceinline__ float gelu_exact(float x) {
    return 0.5f * x * (1.0f + erff(x * 0.70710678118654752f));
}

typedef const unsigned int __attribute__((address_space(1)))* gas_ptr;
typedef unsigned int __attribute__((address_space(3)))* las_ptr;
__device__ __forceinline__ void gload_lds16(const void* g, void* l) {
    __builtin_amdgcn_global_load_lds((gas_ptr)g, (las_ptr)l, 16, 0, 0);
}

// Stage one 128-row x 64-col bf16 half-tile: 8 waves x 2 gloads x 8 rows.
// LDS dest linear; global source col pre-swizzled (granule ^= row&7)  [rule #21]
__device__ __forceinline__ void stage_half(
    const unsigned short* __restrict__ gsrc,
    int ld, unsigned short* ldsdst, int wave)
{
    #pragma unroll
    for (int j = 0; j < 2; ++j) {
        const int r0 = (wave * 2 + j) * 8;
        gload_lds16(gsrc + (size_t)r0 * ld, ldsdst + r0 * 64);
    }
}

#define SBAR()  __builtin_amdgcn_sched_barrier(0)
#define BAR()   do { SBAR(); __builtin_amdgcn_s_barrier(); SBAR(); } while (0)

// ===========================================================================
// gemm8p: 256x256 tile, BK=64, 8 waves, 4 phases/K-tile, quadrant order
// (A0,B0),(A0,B1),(A1,B1),(A1,B0). Stage t+1: A0@p0, B0@p1, B1@p2, A1@p3;
// steady vmcnt(4) at p0/p1/p3 (queue invariant [B1(t),A1(t)] at tile entry).
// ds_reads issued POST-MFMA of the prior phase into just-dead register sets:
//   p0-post: B1(t)->b1r | p1-post: A1(t)->areg | p3-post: A0,B0(t+1)
// so the LDS drain overlaps the MFMA clusters (fix for 43% MfmaUtil plateau).
// ===========================================================================
template<typename TC, int BIAS>
__global__ __launch_bounds__(512, 2) void gemm8p(
    const unsigned short* __restrict__ A, int lda,
    const unsigned short* __restrict__ Bm, int ldb,
    TC* __restrict__ C, int ldc,
    const float* __restrict__ bias, int K, int gridN, int q8)
{
    __shared__ __align__(16) unsigned short lds[2][2][256 * 64]; // [buf][A/B]

    const int tid  = threadIdx.x;
    const int lin  = blockIdx.x;
    const int swz  = (lin & 7) * q8 + (lin >> 3);      // XCD swizzle (nwg%8==0)
    const int bm   = swz / gridN, bn = swz % gridN;

    const int wave = tid >> 6, lane = tid & 63;
    const int wm   = wave >> 2, wn = wave & 3;          // 64-row / 32-col group in quadrant
    const int lrow = lane & 15, lq = lane >> 4;

    const int key = (lrow & 7) << 3;
    const int e0  = (lq << 3) ^ key;
    const int e1  = e0 ^ 32;
    const int aRow = (wm * 64 + lrow) * 64;
    const int bRow = (wn * 32 + lrow) * 64;

    const int grow = lane >> 3;
    const int gswz = ((lane & 7) ^ (grow & 7)) << 3;
    const unsigned short* aS = A  + (size_t)(bm * 256 + grow) * lda + gswz;
    const unsigned short* bS = Bm + (size_t)(bn * 256 + grow) * ldb + gswz;

    f32x4 acc[8][4];
    #pragma unroll
    for (int i = 0; i < 8; ++i)
        #pragma unroll
        for (int n = 0; n < 4; ++n)
            acc[i][n] = (f32x4){0.f, 0.f, 0.f, 0.f};

    bfx8 areg[4][2], b0r[2][2], b1r[2][2];
    const int NT = K >> 6;

    // prologue: tile0 halves A0,B0,B1,A1; vmcnt(4) retires A0,B0 -> invariant queue
    stage_half(aS,                     lda, &lds[0][0][0],        wave);
    stage_half(bS,                     ldb, &lds[0][1][0],        wave);
    stage_half(bS + (size_t)128 * ldb, ldb, &lds[0][1][128 * 64], wave);
    stage_half(aS + (size_t)128 * lda, lda, &lds[0][0][128 * 64], wave);
    asm volatile("s_waitcnt vmcnt(4)" ::: "memory");
    BAR();
    {   // initial A0(t0), B0(t0) reads (once, serial)
        const unsigned short* Ac = lds[0][0];
        const unsigned short* Bc = lds[0][1];
        #pragma unroll
        for (int i = 0; i < 4; ++i) {
            areg[i][0] = *(const bfx8*)(Ac + aRow + i * 1024 + e0);
            areg[i][1] = *(const bfx8*)(Ac + aRow + i * 1024 + e1);
        }
        #pragma unroll
        for (int n = 0; n < 2; ++n) {
            b0r[n][0] = *(const bfx8*)(Bc + bRow + n * 1024 + e0);
            b0r[n][1] = *(const bfx8*)(Bc + bRow + n * 1024 + e1);
        }
    }

    for (int t = 0; t < NT; ++t) {
        const int cur = t & 1, nxt = cur ^ 1;
        const unsigned short* Ac = lds[cur][0];
        const unsigned short* Bc = lds[cur][1];
        const unsigned short* An = lds[nxt][0];
        const unsigned short* Bn = lds[nxt][1];
        const bool hn = (t + 1 < NT);
        const int k1 = (t + 1) << 6;

        // ---- p0: MFMA (A0 x B0); stage t+1:A0; post-read B1(t)
        if (hn) { stage_half(aS + k1, lda, &lds[nxt][0][0], wave);
                  asm volatile("s_waitcnt vmcnt(4)" ::: "memory"); }
        else    { asm volatile("s_waitcnt vmcnt(2)" ::: "memory"); }
        BAR();
        __builtin_amdgcn_s_setprio(1);
        #pragma unroll
        for (int i = 0; i < 4; ++i)
            #pragma unroll
            for (int n = 0; n < 2; ++n)
                #pragma unroll
                for (int kk = 0; kk < 2; ++kk)
                    acc[i][n] = __builtin_amdgcn_mfma_f32_16x16x32_bf16(areg[i][kk], b0r[n][kk], acc[i][n], 0, 0, 0);
        __builtin_amdgcn_s_setprio(0);
        #pragma unroll
        for (int n = 0; n < 2; ++n) {            // B1(t) -> b1r (landed: p0's vmcnt)
            b1r[n][0] = *(const bfx8*)(Bc + 128 * 64 + bRow + n * 1024 + e0);
            b1r[n][1] = *(const bfx8*)(Bc + 128 * 64 + bRow + n * 1024 + e1);
        }
        BAR();

        // ---- p1: MFMA (A0 x B1); stage t+1:B0; post-read A1(t)
        if (hn) { stage_half(bS + k1, ldb, &lds[nxt][1][0], wave);
                  asm volatile("s_waitcnt vmcnt(4)" ::: "memory"); }
        else    { asm volatile("s_waitcnt vmcnt(0)" ::: "memory"); }
        BAR();
        __builtin_amdgcn_s_setprio(1);
        #pragma unroll
        for (int i = 0; i < 4; ++i)
            #pragma unroll
            for (int n = 0; n < 2; ++n)
                #pragma unroll
                for (int kk = 0; kk < 2; ++kk)
                    acc[i][2 + n] = __builtin_amdgcn_mfma_f32_16x16x32_bf16(areg[i][kk], b1r[n][kk], acc[i][2 + n], 0, 0, 0);
        __builtin_amdgcn_s_setprio(0);
        #pragma unroll
        for (int i = 0; i < 4; ++i) {            // A1(t) -> areg (landed: p1's vmcnt)
            areg[i][0] = *(const bfx8*)(Ac + 128 * 64 + aRow + i * 1024 + e0);
            areg[i][1] = *(const bfx8*)(Ac + 128 * 64 + aRow + i * 1024 + e1);
        }
        BAR();

        // ---- p2: MFMA (A1 x B1); stage t+1:B1; no wait, no post-read
        if (hn) stage_half(bS + (size_t)128 * ldb + k1, ldb, &lds[nxt][1][128 * 64], wave);
        BAR();
        __builtin_amdgcn_s_setprio(1);
        #pragma unroll
        for (int i = 0; i < 4; ++i)
            #pragma unroll
            for (int n = 0; n < 2; ++n)
                #pragma unroll
                for (int kk = 0; kk < 2; ++kk)
                    acc[4 + i][2 + n] = __builtin_amdgcn_mfma_f32_16x16x32_bf16(areg[i][kk], b1r[n][kk], acc[4 + i][2 + n], 0, 0, 0);
        __builtin_amdgcn_s_setprio(0);
        BAR();

        // ---- p3: MFMA (A1 x B0); stage t+1:A1; post-read A0,B0(t+1)
        if (hn) { stage_half(aS + (size_t)128 * lda + k1, lda, &lds[nxt][0][128 * 64], wave);
                  asm volatile("s_waitcnt vmcnt(4)" ::: "memory"); }
        BAR();
        __builtin_amdgcn_s_setprio(1);
        #pragma unroll
        for (int i = 0; i < 4; ++i)
            #pragma unroll
            for (int n = 0; n < 2; ++n)
                #pragma unroll
                for (int kk = 0; kk < 2; ++kk)
                    acc[4 + i][n] = __builtin_amdgcn_mfma_f32_16x16x32_bf16(areg[i][kk], b0r[n][kk], acc[4 + i][n], 0, 0, 0);
        __builtin_amdgcn_s_setprio(0);
        if (hn) {   // A0(t+1), B0(t+1) -> areg/b0r (landed: p3's vmcnt(4) retires exactly these)
            #pragma unroll
            for (int i = 0; i < 4; ++i) {
                areg[i][0] = *(const bfx8*)(An + aRow + i * 1024 + e0);
                areg[i][1] = *(const bfx8*)(An + aRow + i * 1024 + e1);
            }
            #pragma unroll
            for (int n = 0; n < 2; ++n) {
                b0r[n][0] = *(const bfx8*)(Bn + bRow + n * 1024 + e0);
                b0r[n][1] = *(const bfx8*)(Bn + bRow + n * 1024 + e1);
            }
        }
        BAR();
    }

    // epilogue: C/D layout col=lane&15, row=(lane>>4)*4+reg
    #pragma unroll
    for (int ai = 0; ai < 8; ++ai) {
        const int a = ai >> 2, i = ai & 3;
        const int row0 = bm * 256 + a * 128 + wm * 64 + i * 16 + lq * 4;
        #pragma unroll
        for (int c = 0; c < 4; ++c) {
            const int col = bn * 256 + (c >> 1) * 128 + wn * 32 + (c & 1) * 16 + lrow;
            float bv = 0.f;
            if (BIAS) bv = bias[col];
            #pragma unroll
            for (int r = 0; r < 4; ++r) {
                const float v = acc[ai][c][r] + bv;
                if constexpr (sizeof(TC) == 2)
                    C[(size_t)(row0 + r) * ldc + col] = (TC)f2bf(v);
                else
                    C[(size_t)(row0 + r) * ldc + col] = (TC)v;
            }
        }
    }
}

// ===========================================================================
// gemm3p: 128x256 tile, BK=64, 8 waves, 2 phases/K-tile, 3-buffer LDS,
// prefetch 2 tiles ahead (unchanged from round 5).
// ===========================================================================
template<typename TC>
__global__ __launch_bounds__(512, 2) void gemm3p(
    const unsigned short* __restrict__ A, int lda,
    const unsigned short* __restrict__ Bm, int ldb,
    TC* __restrict__ C, int ldc, int K, int gridN, int q8)
{
    __shared__ __align__(16) unsigned short lds[3][3 * 128 * 64]; // 144 KiB

    const int tid  = threadIdx.x;
    const int lin  = blockIdx.x;
    const int swz  = (lin & 7) * q8 + (lin >> 3);
    const int bm   = swz / gridN, bn = swz % gridN;

    const int wave = tid >> 6, lane = tid & 63;
    const int wm   = wave >> 2, wn = wave & 3;
    const int lrow = lane & 15, lq = lane >> 4;

    const int key = (lrow & 7) << 3;
    const int e0  = (lq << 3) ^ key;
    const int e1  = e0 ^ 32;
    const int aRow = (wm * 64 + lrow) * 64;
    const int bRow = (wn * 32 + lrow) * 64;

    const int grow = lane >> 3;
    const int gswz = ((lane & 7) ^ (grow & 7)) << 3;
    const unsigned short* aS = A  + (size_t)(bm * 128 + grow) * lda + gswz;
    const unsigned short* bS = Bm + (size_t)(bn * 256 + grow) * ldb + gswz;

    f32x4 acc[4][4];
    #pragma unroll
    for (int i = 0; i < 4; ++i)
        #pragma unroll
        for (int n = 0; n < 4; ++n)
            acc[i][n] = (f32x4){0.f, 0.f, 0.f, 0.f};

    bfx8 areg[4][2], br[2][2];
    const int NT = K >> 6;

    stage_half(aS,                          lda, &lds[0][0],     wave);
    stage_half(bS,                          ldb, &lds[0][8192],  wave);
    stage_half(bS + (size_t)128 * ldb,      ldb, &lds[0][16384], wave);
    stage_half(aS + 64,                     lda, &lds[1][0],     wave);
    stage_half(bS + 64,                     ldb, &lds[1][8192],  wave);
    stage_half(bS + (size_t)128 * ldb + 64, ldb, &lds[1][16384], wave);
    asm volatile("s_waitcnt vmcnt(8)" ::: "memory");
    BAR();

    int cur = 0;
    for (int t = 0; t < NT; ++t) {
        const unsigned short* L = lds[cur];
        int nx2 = cur + 2; if (nx2 >= 3) nx2 -= 3;
        const bool h2 = (t + 2 < NT);
        const int k2 = (t + 2) << 6;

        #pragma unroll
        for (int i = 0; i < 4; ++i) {
            areg[i][0] = *(const bfx8*)(L + aRow + i * 1024 + e0);
            areg[i][1] = *(const bfx8*)(L + aRow + i * 1024 + e1);
        }
        #pragma unroll
        for (int n = 0; n < 2; ++n) {
            br[n][0] = *(const bfx8*)(L + 8192 + bRow + n * 1024 + e0);
            br[n][1] = *(const bfx8*)(L + 8192 + bRow + n * 1024 + e1);
        }
        if (h2) {
            stage_half(aS + k2, lda, &lds[nx2][0],    wave);
            stage_half(bS + k2, ldb, &lds[nx2][8192], wave);
            asm volatile("s_waitcnt vmcnt(10)" ::: "memory");
        } else if (t + 1 < NT) {
            asm volatile("s_waitcnt vmcnt(6)" ::: "memory");
        } else {
            asm volatile("s_waitcnt vmcnt(0)" ::: "memory");
        }
        BAR();
        __builtin_amdgcn_s_setprio(1);
        #pragma unroll
        for (int i = 0; i < 4; ++i)
            #pragma unroll
            for (int n = 0; n < 2; ++n)
                #pragma unroll
                for (int kk = 0; kk < 2; ++kk)
                    acc[i][n] = __builtin_amdgcn_mfma_f32_16x16x32_bf16(areg[i][kk], br[n][kk], acc[i][n], 0, 0, 0);
        __builtin_amdgcn_s_setprio(0);
        BAR();

        #pragma unroll
        for (int n = 0; n < 2; ++n) {
            br[n][0] = *(const bfx8*)(L + 16384 + bRow + n * 1024 + e0);
            br[n][1] = *(const bfx8*)(L + 16384 + bRow + n * 1024 + e1);
        }
        if (h2) {
            stage_half(bS + (size_t)128 * ldb + k2, ldb, &lds[nx2][16384], wave);
            asm volatile("s_waitcnt vmcnt(8)" ::: "memory");
        } else if (t + 1 < NT) {
            asm volatile("s_waitcnt vmcnt(2)" ::: "memory");
        }
        BAR();
        __builtin_amdgcn_s_setprio(1);
        #pragma unroll
        for (int i = 0; i < 4; ++i)
            #pragma unroll
            for (int n = 0; n < 2; ++n)
                #pragma unroll
                for (int kk = 0; kk < 2; ++kk)
                    acc[i][2 + n] = __builtin_amdgcn_mfma_f32_16x16x32_bf16(areg[i][kk], br[n][kk], acc[i][2 + n], 0, 0, 0);
        __builtin_amdgcn_s_setprio(0);
        BAR();

        cur = (cur + 1 == 3) ? 0 : cur + 1;
    }

    #pragma unroll
    for (int i = 0; i < 4; ++i) {
        const int row0 = bm * 128 + wm * 64 + i * 16 + lq * 4;
        #pragma unroll
        for (int c = 0; c < 4; ++c) {
            const int col = bn * 256 + (c >> 1) * 128 + wn * 32 + (c & 1) * 16 + lrow;
            #pragma unroll
            for (int r = 0; r < 4; ++r) {
                const float v = acc[i][c][r];
                if constexpr (sizeof(TC) == 2)
                    C[(size_t)(row0 + r) * ldc + col] = (TC)f2bf(v);
                else
                    C[(size_t)(row0 + r) * ldc + col] = (TC)v;
            }
        }
    }
}

// ===========================================================================
// Fallback 128x128 GEMM (round-3 proven) for small workspace
// ===========================================================================
template<typename T>
__device__ __forceinline__ void stage_op(const T* __restrict__ base, int ld, int k0,
                                         unsigned short* lds_, int tid)
{
    if constexpr (sizeof(T) == 2) {
        const int wave = tid >> 6, lane = tid & 63;
        const int grow = lane >> 3;
        const int gcol = (lane & 7) << 3;
        #pragma unroll
        for (int j = 0; j < 4; ++j) {
            const int r0 = wave * 32 + j * 8;
            gload_lds16((const unsigned short*)base + (size_t)(r0 + grow) * ld + k0 + gcol,
                        &lds_[r0 * 64]);
        }
    } else {
        const int srow = tid >> 4, scol = (tid & 15) << 2;
        #pragma unroll
        for (int p = 0; p < 8; ++p) {
            const int r = p * 16 + srow;
            const float4 v = *(const float4*)((const float*)base + (size_t)r * ld + k0 + scol);
            uint2 w;
            w.x = (unsigned)f2bf(v.x) | ((unsigned)f2bf(v.y) << 16);
            w.y = (unsigned)f2bf(v.z) | ((unsigned)f2bf(v.w) << 16);
            *(uint2*)&lds_[r * 64 + scol] = w;
        }
    }
}

template<typename TA, typename TB, typename TC, int BIAS>
__global__ __launch_bounds__(256) void gemm_bt(
    const TA* __restrict__ A, int lda,
    const TB* __restrict__ Bm, int ldb,
    TC* __restrict__ C, int ldc,
    const float* __restrict__ bias, int K)
{
    __shared__ __align__(16) unsigned short As[128 * 64];
    __shared__ __align__(16) unsigned short Bs[128 * 64];

    const int tid  = threadIdx.x;
    const int bm   = blockIdx.y, bn = blockIdx.x;
    const int wave = tid >> 6,  lane = tid & 63;
    const int wm   = wave >> 1, wn = wave & 1;
    const int lrow = lane & 15, lq = lane >> 4;

    f32x4 acc[4][4];
    #pragma unroll
    for (int i = 0; i < 4; ++i)
        #pragma unroll
        for (int j = 0; j < 4; ++j)
            acc[i][j] = (f32x4){0.f, 0.f, 0.f, 0.f};

    const TA* Abase = A  + (size_t)(bm * 128) * lda;
    const TB* Bbase = Bm + (size_t)(bn * 128) * ldb;

    for (int k0 = 0; k0 < K; k0 += 64) {
        stage_op<TA>(Abase, lda, k0, As, tid);
        stage_op<TB>(Bbase, ldb, k0, Bs, tid);
        __syncthreads();
        #pragma unroll
        for (int kk = 0; kk < 2; ++kk) {
            bfx8 af[4], bfr[4];
            const int kb = kk * 32 + lq * 8;
            #pragma unroll
            for (int m = 0; m < 4; ++m)
                af[m] = *(const bfx8*)&As[(wm * 64 + m * 16 + lrow) * 64 + kb];
            #pragma unroll
            for (int n = 0; n < 4; ++n)
                bfr[n] = *(const bfx8*)&Bs[(wn * 64 + n * 16 + lrow) * 64 + kb];
            #pragma unroll
            for (int m = 0; m < 4; ++m)
                #pragma unroll
                for (int n = 0; n < 4; ++n)
                    acc[m][n] = __builtin_amdgcn_mfma_f32_16x16x32_bf16(af[m], bfr[n], acc[m][n], 0, 0, 0);
        }
        __syncthreads();
    }

    #pragma unroll
    for (int m = 0; m < 4; ++m) {
        #pragma unroll
        for (int n = 0; n < 4; ++n) {
            const int row0 = bm * 128 + wm * 64 + m * 16 + lq * 4;
            const int col  = bn * 128 + wn * 64 + n * 16 + lrow;
            float bv = 0.f;
            if (BIAS) bv = bias[col];
            #pragma unroll
            for (int r = 0; r < 4; ++r) {
                const float v = acc[m][n][r] + bv;
                if constexpr (sizeof(TC) == 2)
                    C[(size_t)(row0 + r) * ldc + col] = (TC)f2bf(v);
                else
                    C[(size_t)(row0 + r) * ldc + col] = (TC)v;
            }
        }
    }
}

// ---------------------------------------------------------------------------
__global__ __launch_bounds__(256) void cvt_bf16(
    const float* __restrict__ in, unsigned short* __restrict__ out, int n8)
{
    const int i = blockIdx.x * 256 + threadIdx.x;
    if (i >= n8) return;
    const float4 a = ((const float4*)in)[i * 2];
    const float4 b = ((const float4*)in)[i * 2 + 1];
    uint4 w;
    w.x = (unsigned)f2bf(a.x) | ((unsigned)f2bf(a.y) << 16);
    w.y = (unsigned)f2bf(a.z) | ((unsigned)f2bf(a.w) << 16);
    w.z = (unsigned)f2bf(b.x) | ((unsigned)f2bf(b.y) << 16);
    w.w = (unsigned)f2bf(b.z) | ((unsigned)f2bf(b.w) << 16);
    ((uint4*)out)[i] = w;
}

// ---------------------------------------------------------------------------
__global__ __launch_bounds__(256) void conv_k(
    const unsigned short* __restrict__ gi, const float* __restrict__ w,
    const float* __restrict__ cb, unsigned short* __restrict__ xc)
{
    const int idx = blockIdx.x * 256 + threadIdx.x;   // BTC*512
    const int h4 = idx & 511, bt = idx >> 9;
    const int h = h4 << 2;
    const int t = bt & (TTC - 1);

    float4 acc = *(const float4*)&cb[h];
    const float4 w0 = *(const float4*)&w[(h + 0) * 4];
    const float4 w1 = *(const float4*)&w[(h + 1) * 4];
    const float4 w2 = *(const float4*)&w[(h + 2) * 4];
    const float4 w3 = *(const float4*)&w[(h + 3) * 4];

    #pragma unroll
    for (int k = 0; k < 4; ++k) {
        const int tt = t - 3 + k;
        if (tt >= 0) {
            const ushort4 v = *(const ushort4*)&gi[(size_t)(bt - 3 + k) * 4096 + 2048 + h];
            const float a0 = (k == 0) ? w0.x : (k == 1) ? w0.y : (k == 2) ? w0.z : w0.w;
            const float a1 = (k == 0) ? w1.x : (k == 1) ? w1.y : (k == 2) ? w1.z : w1.w;
            const float a2 = (k == 0) ? w2.x : (k == 1) ? w2.y : (k == 2) ? w2.z : w2.w;
            const float a3 = (k == 0) ? w3.x : (k == 1) ? w3.y : (k == 2) ? w3.z : w3.w;
            acc.x += a0 * bf2f(v.x); acc.y += a1 * bf2f(v.y);
            acc.z += a2 * bf2f(v.z); acc.w += a3 * bf2f(v.w);
        }
    }
    ushort4 o;
    o.x = f2bf(acc.x); o.y = f2bf(acc.y); o.z = f2bf(acc.z); o.w = f2bf(acc.w);
    *(ushort4*)&xc[(size_t)bt * 2048 + h] = o;
}

// ---------------------------------------------------------------------------
__global__ __launch_bounds__(256) void scan1(
    const unsigned short* __restrict__ g, const unsigned short* __restrict__ xc,
    const float* __restrict__ fb, float2* __restrict__ sums)
{
    const int idx = blockIdx.x * 256 + threadIdx.x;   // 2^19
    const int h = idx & (HIDC - 1);
    const int c = (idx >> 11) & (NCHUNK - 1);
    const int b = idx >> 17;

    const float c1 = -8.0f * log1pf(expf(fb[h]));
    float pA = 1.f, hl = 0.f;
    const int row0 = b * TTC + c * CLEN;

    for (int tl = 0; tl < CLEN; ++tl) {
        const size_t row = (size_t)(row0 + tl);
        const float f   = bf2f(g[row * 4096 + h]);
        const float gin = bf2f(g[row * 4096 + 2048 + h]);
        const float xv  = bf2f(xc[row * 2048 + h]);
        const float sf = 1.f / (1.f + expf(-f));
        const float a  = expf(c1 * sf);
        const float be = sqrtf(1.f - a * a + 1e-6f);
        const float si = 1.f / (1.f + expf(-gin));
        hl = a * hl + be * si * xv;
        pA *= a;
    }
    sums[(size_t)(c * BBC + b) * HIDC + h] = make_float2(pA, hl);
}

__global__ __launch_bounds__(256) void scan2(
    const float2* __restrict__ sums, float* __restrict__ carry)
{
    const int idx = blockIdx.x * 256 + threadIdx.x;   // BBC*HIDC = 8192
    const int h = idx & (HIDC - 1), b = idx >> 11;
    float cy = 0.f;
    for (int c = 0; c < NCHUNK; ++c) {
        carry[(size_t)(c * BBC + b) * HIDC + h] = cy;
        const float2 s = sums[(size_t)(c * BBC + b) * HIDC + h];
        cy = s.y + s.x * cy;
    }
}

__global__ __launch_bounds__(256) void scan3(
    unsigned short* __restrict__ gi, const unsigned short* __restrict__ g,
    const unsigned short* __restrict__ xc, const float* __restrict__ fb,
    const float* __restrict__ carry)
{
    const int idx = blockIdx.x * 256 + threadIdx.x;   // 2^19
    const int h = idx & (HIDC - 1);
    const int c = (idx >> 11) & (NCHUNK - 1);
    const int b = idx >> 17;

    const float c1 = -8.0f * log1pf(expf(fb[h]));
    float hh = carry[(size_t)(c * BBC + b) * HIDC + h];
    const int row0 = b * TTC + c * CLEN;

    for (int tl = 0; tl < CLEN; ++tl) {
        const size_t row = (size_t)(row0 + tl);
        const float f    = bf2f(g[row * 4096 + h]);
        const float gin  = bf2f(g[row * 4096 + 2048 + h]);
        const float xv   = bf2f(xc[row * 2048 + h]);
        const float gate = bf2f(gi[row * 4096 + h]);
        const float sf = 1.f / (1.f + expf(-f));
        const float a  = expf(c1 * sf);
        const float be = sqrtf(1.f - a * a + 1e-6f);
        const float si = 1.f / (1.f + expf(-gin));
        hh = a * hh + be * si * xv;
        gi[row * 4096 + h] = f2bf(gelu_exact(gate) * hh);
    }
}

// ---------------------------------------------------------------------------
extern "C" void kernel_launch(void* const* d_in, const int* in_sizes, int n_in,
                              void* d_out, int out_size, void* d_ws, size_t ws_size,
                              hipStream_t stream)
{
    const float* x     = (const float*)d_in[0];
    const float* W_in  = (const float*)d_in[1];
    const float* cw    = (const float*)d_in[2];
    const float* cb    = (const float*)d_in[3];
    const float* W_g   = (const float*)d_in[4];
    const float* b_g   = (const float*)d_in[5];
    const float* fb    = (const float*)d_in[6];
    const float* W_out = (const float*)d_in[7];
    float* out = (float*)d_out;

    const size_t n_gi  = (size_t)BTC * 4096;            // bf16
    const size_t n_g   = (size_t)BTC * 4096;            // bf16
    const size_t n_xc  = (size_t)BTC * 2048;            // bf16
    const size_t n_sum = (size_t)NCHUNK * BBC * HIDC;   // float2 / float
    const size_t nX    = (size_t)BTC * DIMC;            // x_bf (aliases g)
    const size_t nWin  = (size_t)4096 * 1024;           // (aliases g)
    const size_t nWg   = (size_t)4096 * 2048;
    const size_t nWout = (size_t)1024 * 2048;

    const size_t need_base = (n_gi + n_g + n_xc) * 2 + n_sum * 12;     // 166 MiB
    const size_t need_full = need_base + (nWg + nWout) * 2;            // 186 MiB
    if (ws_size < need_base) return;
    const bool use8 = (ws_size >= need_full);

    unsigned short* gi = (unsigned short*)d_ws;
    unsigned short* g  = gi + n_gi;
    unsigned short* xc = g + n_g;
    float2* sums  = (float2*)(xc + n_xc);
    float*  carry = (float*)(sums + n_sum);
    unsigned short* wg_bf   = (unsigned short*)(carry + n_sum);
    unsigned short* wout_bf = wg_bf + nWg;
    unsigned short* x_bf   = g;            // aliases g (dead until GEMM2)
    unsigned short* win_bf = g + nX;

    if (use8) {
        cvt_bf16<<<(int)(nX    / 8 / 256), 256, 0, stream>>>(x,     x_bf,    (int)(nX    / 8));
        cvt_bf16<<<(int)(nWin  / 8 / 256), 256, 0, stream>>>(W_in,  win_bf,  (int)(nWin  / 8));
        cvt_bf16<<<(int)(nWg   / 8 / 256), 256, 0, stream>>>(W_g,   wg_bf,   (int)(nWg   / 8));
        cvt_bf16<<<(int)(nWout / 8 / 256), 256, 0, stream>>>(W_out, wout_bf, (int)(nWout / 8));

        // GEMM1: gi = x @ W_in^T        M=8192 N=4096 K=1024   nwg=512
        gemm8p<unsigned short, 0><<<512, 512, 0, stream>>>(
            x_bf, DIMC, win_bf, DIMC, gi, 4096, nullptr, DIMC, 16, 64);

        conv_k<<<(BTC * 512) / 256, 256, 0, stream>>>(gi, cw, cb, xc);

        // GEMM2: g = xc @ W_g^T + b_g   M=8192 N=4096 K=2048   nwg=512
        gemm8p<unsigned short, 1><<<512, 512, 0, stream>>>(
            xc, HIDC, wg_bf, HIDC, g, 4096, b_g, HIDC, 16, 64);

        scan1<<<(BBC * NCHUNK * HIDC) / 256, 256, 0, stream>>>(g, xc, fb, sums);
        scan2<<<(BBC * HIDC) / 256, 256, 0, stream>>>(sums, carry);
        scan3<<<(BBC * NCHUNK * HIDC) / 256, 256, 0, stream>>>(gi, g, xc, fb, carry);

        // GEMM3: out = u @ W_out^T      M=8192 N=1024 K=2048   nwg=256 (128x256 tiles)
        gemm3p<float><<<256, 512, 0, stream>>>(
            gi, 4096, wout_bf, HIDC, out, DIMC, HIDC, 4, 32);
    } else {
        gemm_bt<float, float, unsigned short, 0>
            <<<dim3(4096 / 128, BTC / 128), 256, 0, stream>>>(
            x, DIMC, W_in, DIMC, gi, 4096, nullptr, DIMC);
        conv_k<<<(BTC * 512) / 256, 256, 0, stream>>>(gi, cw, cb, xc);
        gemm_bt<unsigned short, float, unsigned short, 1>
            <<<dim3(4096 / 128, BTC / 128), 256, 0, stream>>>(
            xc, HIDC, W_g, HIDC, g, 4096, b_g, HIDC);
        scan1<<<(BBC * NCHUNK * HIDC) / 256, 256, 0, stream>>>(g, xc, fb, sums);
        scan2<<<(BBC * HIDC) / 256, 256, 0, stream>>>(sums, carry);
        scan3<<<(BBC * NCHUNK * HIDC) / 256, 256, 0, stream>>>(gi, g, xc, fb, carry);
        gemm_bt<unsigned short, float, float, 0>
            <<<dim3(DIMC / 128, BTC / 128), 256, 0, stream>>>(
            gi, 4096, W_out, HIDC, out, DIMC, nullptr, HIDC);
    }
}